// Round 2
// baseline (1422.607 us; speedup 1.0000x reference)
//
#include <hip/hip_runtime.h>
#include <float.h>
#include <math.h>

#define EPS 1e-5f
constexpr int B = 4, C = 3, N = 4096, E = 256;
constexpr int KNN = 15;            // 15 neighbors kept (top-16 minus rank 0)
constexpr int BN_ = B * N;         // 16384
constexpr int P = 2;               // points per block in fused kernel

// ---------------- K1: per-channel mean/rstd of x over (B,N) ----------------
__global__ void bn1_stats(const float* __restrict__ x, float* __restrict__ bn1) {
    int c = blockIdx.x, t = threadIdx.x;
    float s = 0.f, ss = 0.f;
    for (int i = t; i < BN_; i += 256) {
        int b = i >> 12, n = i & (N - 1);
        float v = x[(b * C + c) * N + n];
        s += v; ss += v * v;
    }
    __shared__ float rs_[256], rss_[256];
    rs_[t] = s; rss_[t] = ss; __syncthreads();
    for (int w = 128; w > 0; w >>= 1) {
        if (t < w) { rs_[t] += rs_[t + w]; rss_[t] += rss_[t + w]; }
        __syncthreads();
    }
    if (t == 0) {
        float mu = rs_[0] / (float)BN_;
        float var = rss_[0] / (float)BN_ - mu * mu;
        bn1[c] = mu; bn1[3 + c] = rsqrtf(var + EPS);
    }
}

// ---------------- K2: xn (fp32) and x2 = sum_c xn^2 ----------------
__global__ void compute_xn(const float* __restrict__ x,
                           const float* __restrict__ g1,
                           const float* __restrict__ b1,
                           const float* __restrict__ bn1,
                           float* __restrict__ xn, float* __restrict__ x2) {
    int i = blockIdx.x * 256 + threadIdx.x;
    if (i >= BN_) return;
    int b = i >> 12, n = i & (N - 1);
    float sq = 0.f;
    for (int c = 0; c < C; c++) {
        float v = x[(b * C + c) * N + n];
        float xv = (v - bn1[c]) * bn1[3 + c] * g1[c] + b1[c];
        xn[(b * C + c) * N + n] = xv;
        sq += xv * xv;
    }
    x2[i] = sq;
}

// ---------------- K3: per-(b,n) row of d2, iterative top-16 argmax ----------------
// top_k takes the LARGEST d2; rank 0 (farthest) is dropped, ranks 1..15 kept.
__global__ void __launch_bounds__(256) knn_kernel(const float* __restrict__ xn,
                                                  const float* __restrict__ x2,
                                                  unsigned short* __restrict__ idxout) {
    __shared__ float rv[4];
    __shared__ int   ri[4];
    int i = blockIdx.x;
    int b = i >> 12, n = i & (N - 1);
    int t = threadIdx.x;
    const float* xb = xn + b * C * N;
    float a0 = xb[n], a1 = xb[N + n], a2 = xb[2 * N + n];
    float x2n = x2[b * N + n];
    const float* x2b = x2 + b * N;
    float d[16];
    #pragma unroll
    for (int s = 0; s < 16; s++) {
        int m = s * 256 + t;
        float dot = a0 * xb[m] + a1 * xb[N + m] + a2 * xb[2 * N + m];
        d[s] = x2n + x2b[m] - 2.f * dot;
    }
    for (int iter = 0; iter < 16; iter++) {
        // thread-local argmax over 16 register slots (lowest global index wins ties)
        float bv = -FLT_MAX; int bs = 0;
        #pragma unroll
        for (int s = 0; s < 16; s++) {
            if (d[s] > bv) { bv = d[s]; bs = s; }
        }
        int gi = bs * 256 + t;
        // wave butterfly argmax: lexicographic (max value, min index) — associative
        #pragma unroll
        for (int off = 32; off > 0; off >>= 1) {
            float v2 = __shfl_xor(bv, off);
            int   i2 = __shfl_xor(gi, off);
            if (v2 > bv || (v2 == bv && i2 < gi)) { bv = v2; gi = i2; }
        }
        if ((t & 63) == 0) { rv[t >> 6] = bv; ri[t >> 6] = gi; }
        __syncthreads();
        float fv = rv[0]; int fi = ri[0];
        #pragma unroll
        for (int w = 1; w < 4; w++) {
            float v2 = rv[w]; int i2 = ri[w];
            if (v2 > fv || (v2 == fv && i2 < fi)) { fv = v2; fi = i2; }
        }
        if (iter > 0 && t == 0) idxout[i * KNN + (iter - 1)] = (unsigned short)fi;
        // owning thread retires the winning element (keep d[] in registers)
        int wt = fi & 255, wsl = fi >> 8;
        #pragma unroll
        for (int s = 0; s < 16; s++)
            d[s] = (wt == t && wsl == s) ? -FLT_MAX : d[s];
        __syncthreads();
    }
}

// ---------------- K4: cross-moments of neigh over (B,N,K): S1[3], S2[6] ----------------
__global__ void neigh_stats(const float* __restrict__ xn, const unsigned short* __restrict__ idx,
                            float* __restrict__ S) {
    float a[9];
    for (int q = 0; q < 9; q++) a[q] = 0.f;
    const int total = BN_ * KNN;
    for (int i = blockIdx.x * blockDim.x + threadIdx.x; i < total; i += gridDim.x * blockDim.x) {
        int bn = i / KNN;
        int b = bn >> 12, n = bn & (N - 1);
        int j = idx[i];
        const float* xb = xn + b * C * N;
        float v0 = xb[j] - xb[n];
        float v1 = xb[N + j] - xb[N + n];
        float v2 = xb[2 * N + j] - xb[2 * N + n];
        a[0] += v0; a[1] += v1; a[2] += v2;
        a[3] += v0 * v0; a[4] += v1 * v1; a[5] += v2 * v2;
        a[6] += v0 * v1; a[7] += v0 * v2; a[8] += v1 * v2;
    }
    __shared__ float red[256];
    for (int q = 0; q < 9; q++) {
        red[threadIdx.x] = a[q]; __syncthreads();
        for (int w = 128; w > 0; w >>= 1) {
            if (threadIdx.x < w) red[threadIdx.x] += red[threadIdx.x + w];
            __syncthreads();
        }
        if (threadIdx.x == 0) atomicAdd(&S[q], red[0]);
        __syncthreads();
    }
}

// ---------------- K5: closed-form BN2a affine + per-E BN2b scale/shift ----------------
// h is linear in hhat, so BN2b's per-e mean/var follow from the 3x3 cross-moments.
__global__ void finalize_stats(const float* __restrict__ S,
                               const float* __restrict__ g2a, const float* __restrict__ b2a,
                               const float* __restrict__ W2a,
                               const float* __restrict__ g2b, const float* __restrict__ b2b,
                               float* __restrict__ ab, float* __restrict__ sc, float* __restrict__ sh) {
    const float cnt = (float)(BN_ * KNN);
    __shared__ float alpha[3], beta[3], mu[3], Ehh[3][3];
    if (threadIdx.x == 0) {
        float m[3];
        float s2[3][3];
        s2[0][0] = S[3]; s2[1][1] = S[4]; s2[2][2] = S[5];
        s2[0][1] = s2[1][0] = S[6]; s2[0][2] = s2[2][0] = S[7]; s2[1][2] = s2[2][1] = S[8];
        for (int c = 0; c < 3; c++) {
            m[c] = S[c] / cnt;
            float var = s2[c][c] / cnt - m[c] * m[c];
            alpha[c] = g2a[c] * rsqrtf(var + EPS);
            beta[c]  = b2a[c] - m[c] * alpha[c];
            mu[c] = m[c];
            ab[c] = alpha[c]; ab[3 + c] = beta[c];
        }
        for (int c = 0; c < 3; c++)
            for (int cc = 0; cc < 3; cc++)
                Ehh[c][cc] = alpha[c] * alpha[cc] * (s2[c][cc] / cnt)
                           + alpha[c] * beta[cc] * m[c]
                           + beta[c] * alpha[cc] * m[cc]
                           + beta[c] * beta[cc];
    }
    __syncthreads();
    int e = threadIdx.x;
    float w[3], Eh[3];
    for (int c = 0; c < 3; c++) { w[c] = W2a[e * 3 + c]; Eh[c] = alpha[c] * mu[c] + beta[c]; }
    float mean = w[0] * Eh[0] + w[1] * Eh[1] + w[2] * Eh[2];
    float m2 = 0.f;
    for (int c = 0; c < 3; c++)
        for (int cc = 0; cc < 3; cc++) m2 += w[c] * w[cc] * Ehh[c][cc];
    float var = m2 - mean * mean;
    float s = g2b[e] * rsqrtf(var + EPS);
    sc[e] = s;
    sh[e] = b2b[e] - mean * s;
}

// ---------------- K6: fused W2a→BN2b→gelu→W2b→max | point_emb | Wf ----------------
__global__ void __launch_bounds__(256) fused_final(
        const float* __restrict__ xn, const unsigned short* __restrict__ idx,
        const float* __restrict__ ab,
        const float* __restrict__ W2a,
        const float* __restrict__ sc, const float* __restrict__ sh,
        const float* __restrict__ W2b,
        const float* __restrict__ W1, const float* __restrict__ bw1,
        const float* __restrict__ Wf, const float* __restrict__ bfv,
        float* __restrict__ out) {
    __shared__ __align__(16) float hh[P][KNN * E];   // [p][k*E + e] (transposed: conflict-free)
    __shared__ __align__(16) float feat[P][2 * E];
    __shared__ float hhat[P][3][16];
    int i0 = blockIdx.x * P;
    int t = threadIdx.x;
    int b = i0 >> 12;
    int n0 = i0 & (N - 1);
    const float* xb = xn + b * C * N;

    if (t < P * KNN) {   // phase A: gather + BN2a affine
        int p = t / KNN, k = t % KNN;
        int nn = n0 + p;
        int j = idx[(i0 + p) * KNN + k];
        #pragma unroll
        for (int c = 0; c < 3; c++)
            hhat[p][c][k] = ab[c] * (xb[c * N + j] - xb[c * N + nn]) + ab[3 + c];
    }
    __syncthreads();

    {   // phase B: h = W2a @ hhat, BN2b affine, exact gelu; also point_emb
        int e = t;
        float w0 = W2a[e * 3], w1 = W2a[e * 3 + 1], w2 = W2a[e * 3 + 2];
        float s = sc[e], o = sh[e];
        #pragma unroll
        for (int p = 0; p < P; p++) {
            #pragma unroll
            for (int k = 0; k < KNN; k++) {
                float v = s * (w0 * hhat[p][0][k] + w1 * hhat[p][1][k] + w2 * hhat[p][2][k]) + o;
                hh[p][k * E + e] = 0.5f * v * (1.f + erff(v * 0.70710678118654752f));
            }
            feat[p][e] = bw1[e] + W1[e * 3] * xb[n0 + p]
                       + W1[e * 3 + 1] * xb[N + n0 + p] + W1[e * 3 + 2] * xb[2 * N + n0 + p];
        }
    }
    __syncthreads();

    {   // phase C: h2 = W2b @ h ; max over k  (LDS reads are same-address broadcasts)
        int f = t;
        float accA[KNN], accB[KNN];
        #pragma unroll
        for (int k = 0; k < KNN; k++) { accA[k] = 0.f; accB[k] = 0.f; }
        const float4* wrow = (const float4*)(W2b + f * E);
        for (int e4 = 0; e4 < E / 4; e4++) {
            float4 w = wrow[e4];
            #pragma unroll
            for (int k = 0; k < KNN; k++) {
                float4 hA = *(const float4*)&hh[0][k * E + e4 * 4];
                accA[k] += w.x * hA.x + w.y * hA.y + w.z * hA.z + w.w * hA.w;
            }
            #pragma unroll
            for (int k = 0; k < KNN; k++) {
                float4 hB = *(const float4*)&hh[1][k * E + e4 * 4];
                accB[k] += w.x * hB.x + w.y * hB.y + w.z * hB.z + w.w * hB.w;
            }
        }
        float mA = accA[0], mB = accB[0];
        #pragma unroll
        for (int k = 1; k < KNN; k++) { mA = fmaxf(mA, accA[k]); mB = fmaxf(mB, accB[k]); }
        feat[0][E + f] = mA;
        feat[1][E + f] = mB;
    }
    __syncthreads();

    {   // phase D: out = Wf @ feat + bf
        int o = t;
        float a0 = bfv[o], a1 = bfv[o];
        const float4* wr = (const float4*)(Wf + o * 2 * E);
        for (int f4 = 0; f4 < (2 * E) / 4; f4++) {
            float4 w = wr[f4];
            float4 vA = *(const float4*)&feat[0][f4 * 4];
            float4 vB = *(const float4*)&feat[1][f4 * 4];
            a0 += w.x * vA.x + w.y * vA.y + w.z * vA.z + w.w * vA.w;
            a1 += w.x * vB.x + w.y * vB.y + w.z * vB.z + w.w * vB.w;
        }
        out[(b * E + o) * N + n0]     = a0;
        out[(b * E + o) * N + n0 + 1] = a1;
    }
}

extern "C" void kernel_launch(void* const* d_in, const int* in_sizes, int n_in,
                              void* d_out, int out_size, void* d_ws, size_t ws_size,
                              hipStream_t stream) {
    (void)in_sizes; (void)n_in; (void)out_size; (void)ws_size;
    const float* x   = (const float*)d_in[0];
    const float* g1  = (const float*)d_in[1];
    const float* b1  = (const float*)d_in[2];
    const float* W1  = (const float*)d_in[3];
    const float* bw1 = (const float*)d_in[4];
    const float* g2a = (const float*)d_in[5];
    const float* b2a = (const float*)d_in[6];
    const float* W2a = (const float*)d_in[7];
    const float* g2b = (const float*)d_in[8];
    const float* b2b = (const float*)d_in[9];
    const float* W2b = (const float*)d_in[10];
    const float* Wf  = (const float*)d_in[11];
    const float* bfv = (const float*)d_in[12];
    float* out = (float*)d_out;

    // workspace layout (256B-aligned regions), total ~780 KB
    char* ws = (char*)d_ws;
    size_t off = 0;
    auto alloc = [&](size_t bytes) { size_t o = off; off = (off + bytes + 255) & ~(size_t)255; return o; };
    float* xn            = (float*)(ws + alloc(sizeof(float) * B * C * N));
    float* x2            = (float*)(ws + alloc(sizeof(float) * BN_));
    unsigned short* idx  = (unsigned short*)(ws + alloc(sizeof(unsigned short) * BN_ * KNN));
    float* bn1           = (float*)(ws + alloc(sizeof(float) * 8));
    float* S             = (float*)(ws + alloc(sizeof(float) * 16));
    float* ab            = (float*)(ws + alloc(sizeof(float) * 8));
    float* sc            = (float*)(ws + alloc(sizeof(float) * E));
    float* sh            = (float*)(ws + alloc(sizeof(float) * E));

    hipMemsetAsync(S, 0, sizeof(float) * 16, stream);

    bn1_stats<<<C, 256, 0, stream>>>(x, bn1);
    compute_xn<<<BN_ / 256, 256, 0, stream>>>(x, g1, b1, bn1, xn, x2);
    knn_kernel<<<BN_, 256, 0, stream>>>(xn, x2, idx);
    neigh_stats<<<256, 256, 0, stream>>>(xn, idx, S);
    finalize_stats<<<1, 256, 0, stream>>>(S, g2a, b2a, W2a, g2b, b2b, ab, sc, sh);
    fused_final<<<BN_ / P, 256, 0, stream>>>(xn, idx, ab, W2a, sc, sh, W2b, W1, bw1, Wf, bfv, out);
}

// Round 3
// 742.780 us; speedup vs baseline: 1.9152x; 1.9152x over previous
//
#include <hip/hip_runtime.h>
#include <float.h>
#include <math.h>

#define EPS 1e-5f
constexpr int B = 4, C = 3, N = 4096, E = 256;
constexpr int KNN = 15;            // 15 neighbors kept (top-16 minus rank 0)
constexpr int BN_ = B * N;         // 16384
constexpr int P = 4;               // points per block in fused kernel
constexpr int SR  = 264;           // hh_bf row stride (ushorts): 528 B, 16B-aligned, 2-way banks
constexpr int SRF = 520;           // feat_bf row stride (ushorts): 1040 B, 16B-aligned

typedef short bf8 __attribute__((ext_vector_type(8)));   // 8 bf16 in 4 VGPRs
typedef float f4  __attribute__((ext_vector_type(4)));

static __device__ __forceinline__ unsigned short f2bf(float f) {
    union { float f; unsigned int u; } v; v.f = f;
    unsigned int r = v.u + 0x7FFFu + ((v.u >> 16) & 1u);   // RTNE
    return (unsigned short)(r >> 16);
}
static __device__ __forceinline__ bf8 ld_bf8(const unsigned short* p) {
    return *(const bf8*)p;
}

// ---------------- K1: per-channel mean/rstd of x over (B,N) ----------------
__global__ void bn1_stats(const float* __restrict__ x, float* __restrict__ bn1) {
    int c = blockIdx.x, t = threadIdx.x;
    float s = 0.f, ss = 0.f;
    for (int i = t; i < BN_; i += 256) {
        int b = i >> 12, n = i & (N - 1);
        float v = x[(b * C + c) * N + n];
        s += v; ss += v * v;
    }
    __shared__ float rs_[256], rss_[256];
    rs_[t] = s; rss_[t] = ss; __syncthreads();
    for (int w = 128; w > 0; w >>= 1) {
        if (t < w) { rs_[t] += rs_[t + w]; rss_[t] += rss_[t + w]; }
        __syncthreads();
    }
    if (t == 0) {
        float mu = rs_[0] / (float)BN_;
        float var = rss_[0] / (float)BN_ - mu * mu;
        bn1[c] = mu; bn1[3 + c] = rsqrtf(var + EPS);
    }
}

// ---------------- K2: xn (fp32) and x2 = sum_c xn^2 ----------------
__global__ void compute_xn(const float* __restrict__ x,
                           const float* __restrict__ g1,
                           const float* __restrict__ b1,
                           const float* __restrict__ bn1,
                           float* __restrict__ xn, float* __restrict__ x2) {
    int i = blockIdx.x * 256 + threadIdx.x;
    if (i >= BN_) return;
    int b = i >> 12, n = i & (N - 1);
    float sq = 0.f;
    for (int c = 0; c < C; c++) {
        float v = x[(b * C + c) * N + n];
        float xv = (v - bn1[c]) * bn1[3 + c] * g1[c] + b1[c];
        xn[(b * C + c) * N + n] = xv;
        sq += xv * xv;
    }
    x2[i] = sq;
}

// ---------------- K2b: convert W2b / Wf to bf16 ----------------
__global__ void cvt_weights(const float* __restrict__ W2b, const float* __restrict__ Wf,
                            unsigned short* __restrict__ w2b_bf, unsigned short* __restrict__ wf_bf) {
    int i = blockIdx.x * 256 + threadIdx.x;
    if (i < E * E) w2b_bf[i] = f2bf(W2b[i]);
    if (i < E * 2 * E) wf_bf[i] = f2bf(Wf[i]);
}

// ---------------- K3: per-(b,n) row of d2, iterative top-16 argmax ----------------
__global__ void __launch_bounds__(256) knn_kernel(const float* __restrict__ xn,
                                                  const float* __restrict__ x2,
                                                  unsigned short* __restrict__ idxout) {
    __shared__ float rv[4];
    __shared__ int   ri[4];
    int i = blockIdx.x;
    int b = i >> 12, n = i & (N - 1);
    int t = threadIdx.x;
    const float* xb = xn + b * C * N;
    float a0 = xb[n], a1 = xb[N + n], a2 = xb[2 * N + n];
    float x2n = x2[b * N + n];
    const float* x2b = x2 + b * N;
    float d[16];
    #pragma unroll
    for (int s = 0; s < 16; s++) {
        int m = s * 256 + t;
        float dot = a0 * xb[m] + a1 * xb[N + m] + a2 * xb[2 * N + m];
        d[s] = x2n + x2b[m] - 2.f * dot;
    }
    for (int iter = 0; iter < 16; iter++) {
        float bv = -FLT_MAX; int bs = 0;
        #pragma unroll
        for (int s = 0; s < 16; s++) {
            if (d[s] > bv) { bv = d[s]; bs = s; }
        }
        int gi = bs * 256 + t;
        #pragma unroll
        for (int off = 32; off > 0; off >>= 1) {
            float v2 = __shfl_xor(bv, off);
            int   i2 = __shfl_xor(gi, off);
            if (v2 > bv || (v2 == bv && i2 < gi)) { bv = v2; gi = i2; }
        }
        if ((t & 63) == 0) { rv[t >> 6] = bv; ri[t >> 6] = gi; }
        __syncthreads();
        float fv = rv[0]; int fi = ri[0];
        #pragma unroll
        for (int w = 1; w < 4; w++) {
            float v2 = rv[w]; int i2 = ri[w];
            if (v2 > fv || (v2 == fv && i2 < fi)) { fv = v2; fi = i2; }
        }
        if (iter > 0 && t == 0) idxout[i * KNN + (iter - 1)] = (unsigned short)fi;
        int wt = fi & 255, wsl = fi >> 8;
        #pragma unroll
        for (int s = 0; s < 16; s++)
            d[s] = (wt == t && wsl == s) ? -FLT_MAX : d[s];
        __syncthreads();
    }
}

// ---------------- K4: cross-moments of neigh over (B,N,K): S1[3], S2[6] ----------------
__global__ void neigh_stats(const float* __restrict__ xn, const unsigned short* __restrict__ idx,
                            float* __restrict__ S) {
    float a[9];
    for (int q = 0; q < 9; q++) a[q] = 0.f;
    const int total = BN_ * KNN;
    for (int i = blockIdx.x * blockDim.x + threadIdx.x; i < total; i += gridDim.x * blockDim.x) {
        int bn = i / KNN;
        int b = bn >> 12, n = bn & (N - 1);
        int j = idx[i];
        const float* xb = xn + b * C * N;
        float v0 = xb[j] - xb[n];
        float v1 = xb[N + j] - xb[N + n];
        float v2 = xb[2 * N + j] - xb[2 * N + n];
        a[0] += v0; a[1] += v1; a[2] += v2;
        a[3] += v0 * v0; a[4] += v1 * v1; a[5] += v2 * v2;
        a[6] += v0 * v1; a[7] += v0 * v2; a[8] += v1 * v2;
    }
    __shared__ float red[256];
    for (int q = 0; q < 9; q++) {
        red[threadIdx.x] = a[q]; __syncthreads();
        for (int w = 128; w > 0; w >>= 1) {
            if (threadIdx.x < w) red[threadIdx.x] += red[threadIdx.x + w];
            __syncthreads();
        }
        if (threadIdx.x == 0) atomicAdd(&S[q], red[0]);
        __syncthreads();
    }
}

// ---------------- K5: closed-form BN2a affine + per-E BN2b scale/shift ----------------
__global__ void finalize_stats(const float* __restrict__ S,
                               const float* __restrict__ g2a, const float* __restrict__ b2a,
                               const float* __restrict__ W2a,
                               const float* __restrict__ g2b, const float* __restrict__ b2b,
                               float* __restrict__ ab, float* __restrict__ sc, float* __restrict__ sh) {
    const float cnt = (float)(BN_ * KNN);
    __shared__ float alpha[3], beta[3], mu[3], Ehh[3][3];
    if (threadIdx.x == 0) {
        float m[3];
        float s2[3][3];
        s2[0][0] = S[3]; s2[1][1] = S[4]; s2[2][2] = S[5];
        s2[0][1] = s2[1][0] = S[6]; s2[0][2] = s2[2][0] = S[7]; s2[1][2] = s2[2][1] = S[8];
        for (int c = 0; c < 3; c++) {
            m[c] = S[c] / cnt;
            float var = s2[c][c] / cnt - m[c] * m[c];
            alpha[c] = g2a[c] * rsqrtf(var + EPS);
            beta[c]  = b2a[c] - m[c] * alpha[c];
            mu[c] = m[c];
            ab[c] = alpha[c]; ab[3 + c] = beta[c];
        }
        for (int c = 0; c < 3; c++)
            for (int cc = 0; cc < 3; cc++)
                Ehh[c][cc] = alpha[c] * alpha[cc] * (s2[c][cc] / cnt)
                           + alpha[c] * beta[cc] * m[c]
                           + beta[c] * alpha[cc] * m[cc]
                           + beta[c] * beta[cc];
    }
    __syncthreads();
    int e = threadIdx.x;
    float w[3], Eh[3];
    for (int c = 0; c < 3; c++) { w[c] = W2a[e * 3 + c]; Eh[c] = alpha[c] * mu[c] + beta[c]; }
    float mean = w[0] * Eh[0] + w[1] * Eh[1] + w[2] * Eh[2];
    float m2 = 0.f;
    for (int c = 0; c < 3; c++)
        for (int cc = 0; cc < 3; cc++) m2 += w[c] * w[cc] * Ehh[c][cc];
    float var = m2 - mean * mean;
    float s = g2b[e] * rsqrtf(var + EPS);
    sc[e] = s;
    sh[e] = b2b[e] - mean * s;
}

// ---------------- K6: fused W2a→BN2b→gelu→[MFMA W2b]→max | point_emb | [MFMA Wf] ----------------
// P=4 points/block; hh cols padded to 16/point (col 15 duplicates col 0: max-safe).
__global__ void __launch_bounds__(256) fused_final(
        const float* __restrict__ xn, const unsigned short* __restrict__ idx,
        const float* __restrict__ ab,
        const float* __restrict__ W2a,
        const float* __restrict__ sc, const float* __restrict__ sh,
        const unsigned short* __restrict__ w2b_bf,
        const float* __restrict__ W1, const float* __restrict__ bw1,
        const unsigned short* __restrict__ wf_bf, const float* __restrict__ bfv,
        float* __restrict__ out) {
    __shared__ __align__(16) unsigned short hh_bf[64 * SR];     // row n=16p+k, col e (bf16)
    __shared__ __align__(16) unsigned short feat_bf[16 * SRF];  // row p (4 valid), col f 0..511 (bf16)
    __shared__ float hhat[P][3][16];
    int i0 = blockIdx.x * P;
    int t = threadIdx.x;
    int b = i0 >> 12, n0 = i0 & (N - 1);
    const float* xb = xn + b * C * N;

    if (t < P * KNN) {   // phase A: gather + BN2a affine
        int p = t / KNN, k = t % KNN;
        int nn = n0 + p;
        int j = idx[(i0 + p) * KNN + k];
        #pragma unroll
        for (int c = 0; c < 3; c++)
            hhat[p][c][k] = ab[c] * (xb[c * N + j] - xb[c * N + nn]) + ab[3 + c];
    }
    __syncthreads();

    {   // phase B: h = W2a @ hhat, BN2b affine, exact gelu (bf16 to LDS); point_emb
        int e = t;
        float w0 = W2a[e * 3], w1 = W2a[e * 3 + 1], w2 = W2a[e * 3 + 2];
        float s = sc[e], o = sh[e];
        #pragma unroll
        for (int p = 0; p < P; p++) {
            float g0 = 0.f;
            #pragma unroll
            for (int k = 0; k < KNN; k++) {
                float v = s * (w0 * hhat[p][0][k] + w1 * hhat[p][1][k] + w2 * hhat[p][2][k]) + o;
                float g = 0.5f * v * (1.f + erff(v * 0.70710678118654752f));
                hh_bf[(16 * p + k) * SR + e] = f2bf(g);
                if (k == 0) g0 = g;
            }
            hh_bf[(16 * p + 15) * SR + e] = f2bf(g0);   // dup col: max unaffected
            feat_bf[p * SRF + e] = f2bf(bw1[e] + W1[e * 3] * xb[n0 + p]
                       + W1[e * 3 + 1] * xb[N + n0 + p] + W1[e * 3 + 2] * xb[2 * N + n0 + p]);
        }
    }
    __syncthreads();

    int w = t >> 6, lane = t & 63;
    int m = lane & 15, q = lane >> 4;

    {   // phase C: h2 = W2b @ hh via MFMA; max over k -> feat_bf[:,256:512]
        // wave w: f-half h2_ = w>>1 (8 tiles of 16 rows), point pair pp = w&1
        int fh = w >> 1, pp = w & 1;
        bf8 bfr[2][8];
        #pragma unroll
        for (int pi = 0; pi < 2; pi++) {
            int p = pp * 2 + pi;
            #pragma unroll
            for (int kb = 0; kb < 8; kb++)
                bfr[pi][kb] = ld_bf8(&hh_bf[(16 * p + m) * SR + kb * 32 + q * 8]);
        }
        for (int ft = 0; ft < 8; ft++) {
            int fbase = (fh * 8 + ft) * 16;
            bf8 a[8];
            #pragma unroll
            for (int kb = 0; kb < 8; kb++)
                a[kb] = ld_bf8(&w2b_bf[(fbase + m) * 256 + kb * 32 + q * 8]);
            #pragma unroll
            for (int pi = 0; pi < 2; pi++) {
                f4 acc = {0.f, 0.f, 0.f, 0.f};
                #pragma unroll
                for (int kb = 0; kb < 8; kb++)
                    acc = __builtin_amdgcn_mfma_f32_16x16x32_bf16(a[kb], bfr[pi][kb], acc, 0, 0, 0);
                // D layout: col=lane&15 (k-col), row=4q+reg -> max over cols via 16-lane butterfly
                float v0 = acc[0], v1 = acc[1], v2 = acc[2], v3 = acc[3];
                #pragma unroll
                for (int off = 1; off < 16; off <<= 1) {
                    v0 = fmaxf(v0, __shfl_xor(v0, off));
                    v1 = fmaxf(v1, __shfl_xor(v1, off));
                    v2 = fmaxf(v2, __shfl_xor(v2, off));
                    v3 = fmaxf(v3, __shfl_xor(v3, off));
                }
                if (m == 0) {
                    int p = pp * 2 + pi;
                    unsigned short* fb = &feat_bf[p * SRF + E + fbase + 4 * q];
                    fb[0] = f2bf(v0); fb[1] = f2bf(v1); fb[2] = f2bf(v2); fb[3] = f2bf(v3);
                }
            }
        }
    }
    __syncthreads();

    {   // phase D: out = Wf @ feat^T via MFMA (cols = points, 4 of 16 valid)
        for (int ot = 0; ot < 4; ot++) {
            int obase = (w * 4 + ot) * 16;
            f4 acc = {0.f, 0.f, 0.f, 0.f};
            #pragma unroll
            for (int kb = 0; kb < 16; kb++) {
                bf8 a = ld_bf8(&wf_bf[(obase + m) * 512 + kb * 32 + q * 8]);
                bf8 bb = ld_bf8(&feat_bf[m * SRF + kb * 32 + q * 8]);
                acc = __builtin_amdgcn_mfma_f32_16x16x32_bf16(a, bb, acc, 0, 0, 0);
            }
            if (m < P) {   // col = m = point; row = obase + 4q + reg
                int o0 = obase + 4 * q;
                out[(b * E + o0 + 0) * N + n0 + m] = acc[0] + bfv[o0 + 0];
                out[(b * E + o0 + 1) * N + n0 + m] = acc[1] + bfv[o0 + 1];
                out[(b * E + o0 + 2) * N + n0 + m] = acc[2] + bfv[o0 + 2];
                out[(b * E + o0 + 3) * N + n0 + m] = acc[3] + bfv[o0 + 3];
            }
        }
    }
}

extern "C" void kernel_launch(void* const* d_in, const int* in_sizes, int n_in,
                              void* d_out, int out_size, void* d_ws, size_t ws_size,
                              hipStream_t stream) {
    (void)in_sizes; (void)n_in; (void)out_size; (void)ws_size;
    const float* x   = (const float*)d_in[0];
    const float* g1  = (const float*)d_in[1];
    const float* b1  = (const float*)d_in[2];
    const float* W1  = (const float*)d_in[3];
    const float* bw1 = (const float*)d_in[4];
    const float* g2a = (const float*)d_in[5];
    const float* b2a = (const float*)d_in[6];
    const float* W2a = (const float*)d_in[7];
    const float* g2b = (const float*)d_in[8];
    const float* b2b = (const float*)d_in[9];
    const float* W2b = (const float*)d_in[10];
    const float* Wf  = (const float*)d_in[11];
    const float* bfv = (const float*)d_in[12];
    float* out = (float*)d_out;

    char* ws = (char*)d_ws;
    size_t off = 0;
    auto alloc = [&](size_t bytes) { size_t o = off; off = (off + bytes + 255) & ~(size_t)255; return o; };
    float* xn             = (float*)(ws + alloc(sizeof(float) * B * C * N));
    float* x2             = (float*)(ws + alloc(sizeof(float) * BN_));
    unsigned short* idx   = (unsigned short*)(ws + alloc(sizeof(unsigned short) * BN_ * KNN));
    float* bn1            = (float*)(ws + alloc(sizeof(float) * 8));
    float* S              = (float*)(ws + alloc(sizeof(float) * 16));
    float* ab             = (float*)(ws + alloc(sizeof(float) * 8));
    float* sc             = (float*)(ws + alloc(sizeof(float) * E));
    float* sh             = (float*)(ws + alloc(sizeof(float) * E));
    unsigned short* w2bbf = (unsigned short*)(ws + alloc(sizeof(unsigned short) * E * E));
    unsigned short* wfbf  = (unsigned short*)(ws + alloc(sizeof(unsigned short) * E * 2 * E));

    hipMemsetAsync(S, 0, sizeof(float) * 16, stream);

    bn1_stats<<<C, 256, 0, stream>>>(x, bn1);
    compute_xn<<<BN_ / 256, 256, 0, stream>>>(x, g1, b1, bn1, xn, x2);
    cvt_weights<<<(E * 2 * E) / 256, 256, 0, stream>>>(W2b, Wf, w2bbf, wfbf);
    knn_kernel<<<BN_, 256, 0, stream>>>(xn, x2, idx);
    neigh_stats<<<256, 256, 0, stream>>>(xn, idx, S);
    finalize_stats<<<1, 256, 0, stream>>>(S, g2a, b2a, W2a, g2b, b2b, ab, sc, sh);
    fused_final<<<BN_ / P, 256, 0, stream>>>(xn, idx, ab, W2a, sc, sh, w2bbf, W1, bw1, wfbf, bfv, out);
}

// Round 4
// 524.986 us; speedup vs baseline: 2.7098x; 1.4149x over previous
//
#include <hip/hip_runtime.h>
#include <float.h>
#include <math.h>

#define EPS 1e-5f
constexpr int B = 4, C = 3, N = 4096, E = 256;
constexpr int KNN = 15;            // 15 neighbors kept (top-16 minus rank 0)
constexpr int BN_ = B * N;         // 16384
constexpr int P = 4;               // points per block in fused kernel
constexpr int SR  = 264;           // hh_bf row stride (ushorts): 528 B, 16B-aligned
constexpr int SRF = 520;           // feat_bf row stride (ushorts): 1040 B, 16B-aligned

typedef short bf8 __attribute__((ext_vector_type(8)));   // 8 bf16 in 4 VGPRs
typedef float f4  __attribute__((ext_vector_type(4)));

static __device__ __forceinline__ unsigned short f2bf(float f) {
    union { float f; unsigned int u; } v; v.f = f;
    unsigned int r = v.u + 0x7FFFu + ((v.u >> 16) & 1u);   // RTNE
    return (unsigned short)(r >> 16);
}
static __device__ __forceinline__ bf8 ld_bf8(const unsigned short* p) {
    return *(const bf8*)p;
}
// gelu with A&S 7.1.26 erf (|err| < 1.5e-7): ~14 VALU inst vs ~50 for libm erff
static __device__ __forceinline__ float gelu_f(float v) {
    float u = fabsf(v) * 0.70710678118654752f;
    float tt = __builtin_amdgcn_rcpf(1.f + 0.3275911f * u);
    float poly = tt * (0.254829592f + tt * (-0.284496736f + tt * (1.421413741f
               + tt * (-1.453152027f + tt * 1.061405429f))));
    float erfu = 1.f - poly * __expf(-u * u);   // erf(|v|/sqrt2)
    float cdf = 0.5f + 0.5f * (v < 0.f ? -erfu : erfu);
    return v * cdf;
}

// ---------------- K1: per-channel mean/rstd of x over (B,N) ----------------
__global__ void bn1_stats(const float* __restrict__ x, float* __restrict__ bn1) {
    int c = blockIdx.x, t = threadIdx.x;
    float s = 0.f, ss = 0.f;
    for (int i4 = t; i4 < BN_ / 4; i4 += 256) {
        int b = i4 >> 10, n4 = i4 & 1023;
        float4 v = ((const float4*)(x + (b * C + c) * N))[n4];
        s += v.x + v.y + v.z + v.w;
        ss += v.x * v.x + v.y * v.y + v.z * v.z + v.w * v.w;
    }
    __shared__ float rs_[256], rss_[256];
    rs_[t] = s; rss_[t] = ss; __syncthreads();
    for (int w = 128; w > 0; w >>= 1) {
        if (t < w) { rs_[t] += rs_[t + w]; rss_[t] += rss_[t + w]; }
        __syncthreads();
    }
    if (t == 0) {
        float mu = rs_[0] / (float)BN_;
        float var = rss_[0] / (float)BN_ - mu * mu;
        bn1[c] = mu; bn1[3 + c] = rsqrtf(var + EPS);
    }
}

// ---------------- K2: xn4 = (xn_x, xn_y, xn_z, sum xn^2) AoS ----------------
__global__ void compute_xn(const float* __restrict__ x,
                           const float* __restrict__ g1,
                           const float* __restrict__ b1,
                           const float* __restrict__ bn1,
                           float4* __restrict__ xn4) {
    int i = blockIdx.x * 256 + threadIdx.x;
    if (i >= BN_) return;
    int b = i >> 12, n = i & (N - 1);
    float v[3];
    #pragma unroll
    for (int c = 0; c < C; c++) {
        float xv = (x[(b * C + c) * N + n] - bn1[c]) * bn1[3 + c] * g1[c] + b1[c];
        v[c] = xv;
    }
    float4 o; o.x = v[0]; o.y = v[1]; o.z = v[2];
    o.w = v[0] * v[0] + v[1] * v[1] + v[2] * v[2];
    xn4[i] = o;
}

// ---------------- K2b: convert W2b / Wf to bf16 ----------------
__global__ void cvt_weights(const float* __restrict__ W2b, const float* __restrict__ Wf,
                            unsigned short* __restrict__ w2b_bf, unsigned short* __restrict__ wf_bf) {
    int i = blockIdx.x * 256 + threadIdx.x;
    if (i < E * E) w2b_bf[i] = f2bf(W2b[i]);
    if (i < E * 2 * E) wf_bf[i] = f2bf(Wf[i]);
}

// ---------------- K3: top-16 (largest d2) per point + fused neigh moments ----------------
__global__ void __launch_bounds__(256) knn_kernel(const float4* __restrict__ xn4,
                                                  unsigned short* __restrict__ idxout,
                                                  float* __restrict__ S9) {
    __shared__ float rv[2][4];
    __shared__ int   ri[2][4];
    __shared__ float smom[15][9];
    int i = blockIdx.x;
    int b = i >> 12, n = i & (N - 1);
    int t = threadIdx.x;
    const float4* xb = xn4 + b * N;
    float4 qv = xb[n];
    float d[16];
    float bv = -FLT_MAX; int bs = 0;
    #pragma unroll
    for (int s = 0; s < 16; s++) {
        int m = s * 256 + t;
        float4 p = xb[m];
        float dot = qv.x * p.x + qv.y * p.y + qv.z * p.z;
        float dd = qv.w + p.w - 2.f * dot;
        d[s] = dd;
        if (dd > bv) { bv = dd; bs = s; }
    }
    int gi = bs * 256 + t;
    int myj = 0;
    int w = t >> 6;
    for (int iter = 0; iter < 16; iter++) {
        float wv = bv; int wi = gi;
        #pragma unroll
        for (int off = 32; off > 0; off >>= 1) {
            float v2 = __shfl_xor(wv, off);
            int   i2 = __shfl_xor(wi, off);
            if (v2 > wv || (v2 == wv && i2 < wi)) { wv = v2; wi = i2; }
        }
        int par = iter & 1;
        if ((t & 63) == 0) { rv[par][w] = wv; ri[par][w] = wi; }
        __syncthreads();
        float fv = rv[par][0]; int fi = ri[par][0];
        #pragma unroll
        for (int u = 1; u < 4; u++) {
            float v2 = rv[par][u]; int i2 = ri[par][u];
            if (v2 > fv || (v2 == fv && i2 < fi)) { fv = v2; fi = i2; }
        }
        if (iter == t + 1) myj = fi;     // threads 0..14 capture ranks 1..15
        if ((fi & 255) == t) {           // owner retires & rescans (1 thread)
            d[fi >> 8] = -FLT_MAX;
            bv = -FLT_MAX; bs = 0;
            #pragma unroll
            for (int s = 0; s < 16; s++)
                if (d[s] > bv) { bv = d[s]; bs = s; }
            gi = bs * 256 + t;
        }
    }
    if (t < 15) {
        idxout[i * KNN + t] = (unsigned short)myj;
        float4 p = xb[myj];
        float v0 = p.x - qv.x, v1 = p.y - qv.y, v2 = p.z - qv.z;
        float* mm = smom[t];
        mm[0] = v0; mm[1] = v1; mm[2] = v2;
        mm[3] = v0 * v0; mm[4] = v1 * v1; mm[5] = v2 * v2;
        mm[6] = v0 * v1; mm[7] = v0 * v2; mm[8] = v1 * v2;
    }
    __syncthreads();
    if (t < 9) {
        float a = 0.f;
        #pragma unroll
        for (int u = 0; u < 15; u++) a += smom[u][t];
        atomicAdd(&S9[(i & 63) * 9 + t], a);
    }
}

// ---------------- K5: closed-form BN2a affine + per-E BN2b scale/shift ----------------
__global__ void finalize_stats(const float* __restrict__ S9,
                               const float* __restrict__ g2a, const float* __restrict__ b2a,
                               const float* __restrict__ W2a,
                               const float* __restrict__ g2b, const float* __restrict__ b2b,
                               float* __restrict__ ab, float* __restrict__ sc, float* __restrict__ sh) {
    const float cnt = (float)(BN_ * KNN);
    __shared__ float S[9];
    __shared__ float alpha[3], beta[3], mu[3], Ehh[3][3];
    int t = threadIdx.x;
    if (t < 9) {
        float a = 0.f;
        for (int u = 0; u < 64; u++) a += S9[u * 9 + t];
        S[t] = a;
    }
    __syncthreads();
    if (t == 0) {
        float m[3];
        float s2[3][3];
        s2[0][0] = S[3]; s2[1][1] = S[4]; s2[2][2] = S[5];
        s2[0][1] = s2[1][0] = S[6]; s2[0][2] = s2[2][0] = S[7]; s2[1][2] = s2[2][1] = S[8];
        for (int c = 0; c < 3; c++) {
            m[c] = S[c] / cnt;
            float var = s2[c][c] / cnt - m[c] * m[c];
            alpha[c] = g2a[c] * rsqrtf(var + EPS);
            beta[c]  = b2a[c] - m[c] * alpha[c];
            mu[c] = m[c];
            ab[c] = alpha[c]; ab[3 + c] = beta[c];
        }
        for (int c = 0; c < 3; c++)
            for (int cc = 0; cc < 3; cc++)
                Ehh[c][cc] = alpha[c] * alpha[cc] * (s2[c][cc] / cnt)
                           + alpha[c] * beta[cc] * m[c]
                           + beta[c] * alpha[cc] * m[cc]
                           + beta[c] * beta[cc];
    }
    __syncthreads();
    int e = t;
    float wv[3], Eh[3];
    for (int c = 0; c < 3; c++) { wv[c] = W2a[e * 3 + c]; Eh[c] = alpha[c] * mu[c] + beta[c]; }
    float mean = wv[0] * Eh[0] + wv[1] * Eh[1] + wv[2] * Eh[2];
    float m2 = 0.f;
    for (int c = 0; c < 3; c++)
        for (int cc = 0; cc < 3; cc++) m2 += wv[c] * wv[cc] * Ehh[c][cc];
    float var = m2 - mean * mean;
    float s = g2b[e] * rsqrtf(var + EPS);
    sc[e] = s;
    sh[e] = b2b[e] - mean * s;
}

// ---------------- K6: fused W2a→BN2b→gelu→[MFMA W2b]→max | point_emb | [MFMA Wf] ----------------
__global__ void __launch_bounds__(256, 4) fused_final(
        const float4* __restrict__ xn4, const unsigned short* __restrict__ idx,
        const float* __restrict__ ab,
        const float* __restrict__ W2a,
        const float* __restrict__ sc, const float* __restrict__ sh,
        const unsigned short* __restrict__ w2b_bf,
        const float* __restrict__ W1, const float* __restrict__ bw1,
        const unsigned short* __restrict__ wf_bf, const float* __restrict__ bfv,
        float* __restrict__ out) {
    __shared__ __align__(16) unsigned short hh_bf[64 * SR];    // row n=16p+k, col e (bf16)
    __shared__ __align__(16) unsigned short feat_bf[4 * SRF];  // row p, col f 0..511 (bf16)
    __shared__ float hhat[P][3][16];
    int i0 = blockIdx.x * P;
    int t = threadIdx.x;
    int b = i0 >> 12, n0 = i0 & (N - 1);
    const float4* xb = xn4 + b * N;

    if (t < P * KNN) {   // phase A: gather + BN2a affine
        int p = t / KNN, k = t % KNN;
        int j = idx[(i0 + p) * KNN + k];
        float4 pj = xb[j];
        float4 pn = xb[n0 + p];
        hhat[p][0][k] = ab[0] * (pj.x - pn.x) + ab[3];
        hhat[p][1][k] = ab[1] * (pj.y - pn.y) + ab[4];
        hhat[p][2][k] = ab[2] * (pj.z - pn.z) + ab[5];
    }
    __syncthreads();

    {   // phase B: h = W2a @ hhat, BN2b affine, gelu (bf16 to LDS); point_emb
        int e = t;
        float w0 = W2a[e * 3], w1 = W2a[e * 3 + 1], w2 = W2a[e * 3 + 2];
        float s = sc[e], o = sh[e];
        #pragma unroll
        for (int p = 0; p < P; p++) {
            float g0 = 0.f;
            #pragma unroll
            for (int k = 0; k < KNN; k++) {
                float v = s * (w0 * hhat[p][0][k] + w1 * hhat[p][1][k] + w2 * hhat[p][2][k]) + o;
                float g = gelu_f(v);
                hh_bf[(16 * p + k) * SR + e] = f2bf(g);
                if (k == 0) g0 = g;
            }
            hh_bf[(16 * p + 15) * SR + e] = f2bf(g0);   // dup col: max unaffected
            float4 pv = xb[n0 + p];
            feat_bf[p * SRF + e] = f2bf(bw1[e] + W1[e * 3] * pv.x
                       + W1[e * 3 + 1] * pv.y + W1[e * 3 + 2] * pv.z);
        }
    }
    __syncthreads();

    int w = t >> 6, lane = t & 63;
    int m = lane & 15, q = lane >> 4;

    {   // phase C: h2 = W2b @ hh via MFMA; max over k -> feat_bf[:,256:512]
        int fh = w >> 1, pp = w & 1;
        bf8 bfr[2][8];
        #pragma unroll
        for (int pi = 0; pi < 2; pi++) {
            int p = pp * 2 + pi;
            #pragma unroll
            for (int kb = 0; kb < 8; kb++)
                bfr[pi][kb] = ld_bf8(&hh_bf[(16 * p + m) * SR + kb * 32 + q * 8]);
        }
        for (int ft = 0; ft < 8; ft++) {
            int fbase = (fh * 8 + ft) * 16;
            bf8 a[8];
            #pragma unroll
            for (int kb = 0; kb < 8; kb++)
                a[kb] = ld_bf8(&w2b_bf[(fbase + m) * 256 + kb * 32 + q * 8]);
            #pragma unroll
            for (int pi = 0; pi < 2; pi++) {
                f4 acc = {0.f, 0.f, 0.f, 0.f};
                #pragma unroll
                for (int kb = 0; kb < 8; kb++)
                    acc = __builtin_amdgcn_mfma_f32_16x16x32_bf16(a[kb], bfr[pi][kb], acc, 0, 0, 0);
                float v0 = acc[0], v1 = acc[1], v2 = acc[2], v3 = acc[3];
                #pragma unroll
                for (int off = 1; off < 16; off <<= 1) {
                    v0 = fmaxf(v0, __shfl_xor(v0, off));
                    v1 = fmaxf(v1, __shfl_xor(v1, off));
                    v2 = fmaxf(v2, __shfl_xor(v2, off));
                    v3 = fmaxf(v3, __shfl_xor(v3, off));
                }
                if (m == 0) {
                    int p = pp * 2 + pi;
                    unsigned short* fb = &feat_bf[p * SRF + E + fbase + 4 * q];
                    fb[0] = f2bf(v0); fb[1] = f2bf(v1); fb[2] = f2bf(v2); fb[3] = f2bf(v3);
                }
            }
        }
    }
    __syncthreads();

    {   // phase D: out = Wf @ feat^T via MFMA (cols = points; rows m>=4 alias p=m&3, discarded)
        for (int ot = 0; ot < 4; ot++) {
            int obase = (w * 4 + ot) * 16;
            f4 acc = {0.f, 0.f, 0.f, 0.f};
            #pragma unroll
            for (int kb = 0; kb < 16; kb++) {
                bf8 a = ld_bf8(&wf_bf[(obase + m) * 512 + kb * 32 + q * 8]);
                bf8 bb = ld_bf8(&feat_bf[(m & 3) * SRF + kb * 32 + q * 8]);
                acc = __builtin_amdgcn_mfma_f32_16x16x32_bf16(a, bb, acc, 0, 0, 0);
            }
            if (m < P) {   // col = m = point; row = obase + 4q + reg
                int o0 = obase + 4 * q;
                out[(b * E + o0 + 0) * N + n0 + m] = acc[0] + bfv[o0 + 0];
                out[(b * E + o0 + 1) * N + n0 + m] = acc[1] + bfv[o0 + 1];
                out[(b * E + o0 + 2) * N + n0 + m] = acc[2] + bfv[o0 + 2];
                out[(b * E + o0 + 3) * N + n0 + m] = acc[3] + bfv[o0 + 3];
            }
        }
    }
}

extern "C" void kernel_launch(void* const* d_in, const int* in_sizes, int n_in,
                              void* d_out, int out_size, void* d_ws, size_t ws_size,
                              hipStream_t stream) {
    (void)in_sizes; (void)n_in; (void)out_size; (void)ws_size;
    const float* x   = (const float*)d_in[0];
    const float* g1  = (const float*)d_in[1];
    const float* b1  = (const float*)d_in[2];
    const float* W1  = (const float*)d_in[3];
    const float* bw1 = (const float*)d_in[4];
    const float* g2a = (const float*)d_in[5];
    const float* b2a = (const float*)d_in[6];
    const float* W2a = (const float*)d_in[7];
    const float* g2b = (const float*)d_in[8];
    const float* b2b = (const float*)d_in[9];
    const float* W2b = (const float*)d_in[10];
    const float* Wf  = (const float*)d_in[11];
    const float* bfv = (const float*)d_in[12];
    float* out = (float*)d_out;

    char* ws = (char*)d_ws;
    size_t off = 0;
    auto alloc = [&](size_t bytes) { size_t o = off; off = (off + bytes + 255) & ~(size_t)255; return o; };
    float4* xn4           = (float4*)(ws + alloc(sizeof(float4) * BN_));
    unsigned short* idx   = (unsigned short*)(ws + alloc(sizeof(unsigned short) * BN_ * KNN));
    float* bn1            = (float*)(ws + alloc(sizeof(float) * 8));
    float* S9             = (float*)(ws + alloc(sizeof(float) * 64 * 9));
    float* ab             = (float*)(ws + alloc(sizeof(float) * 8));
    float* sc             = (float*)(ws + alloc(sizeof(float) * E));
    float* sh             = (float*)(ws + alloc(sizeof(float) * E));
    unsigned short* w2bbf = (unsigned short*)(ws + alloc(sizeof(unsigned short) * E * E));
    unsigned short* wfbf  = (unsigned short*)(ws + alloc(sizeof(unsigned short) * E * 2 * E));

    hipMemsetAsync(S9, 0, sizeof(float) * 64 * 9, stream);

    bn1_stats<<<C, 256, 0, stream>>>(x, bn1);
    compute_xn<<<BN_ / 256, 256, 0, stream>>>(x, g1, b1, bn1, xn4);
    cvt_weights<<<(E * 2 * E) / 256, 256, 0, stream>>>(W2b, Wf, w2bbf, wfbf);
    knn_kernel<<<BN_, 256, 0, stream>>>(xn4, idx, S9);
    finalize_stats<<<1, 256, 0, stream>>>(S9, g2a, b2a, W2a, g2b, b2b, ab, sc, sh);
    fused_final<<<BN_ / P, 256, 0, stream>>>(xn4, idx, ab, W2a, sc, sh, w2bbf, W1, bw1, wfbf, bfv, out);
}

// Round 5
// 423.461 us; speedup vs baseline: 3.3595x; 1.2398x over previous
//
#include <hip/hip_runtime.h>
#include <float.h>
#include <math.h>

#define EPS 1e-5f
constexpr int B = 4, C = 3, N = 4096, E = 256;
constexpr int KNN = 15;            // 15 neighbors kept (top-16 minus rank 0)
constexpr int BN_ = B * N;         // 16384
constexpr int P = 4;               // points per block in fused kernel
constexpr int SR  = 264;           // hh_bf row stride (ushorts)
constexpr int SRF = 520;           // feat_bf row stride (ushorts)

typedef short bf8 __attribute__((ext_vector_type(8)));   // 8 bf16 in 4 VGPRs
typedef float f4  __attribute__((ext_vector_type(4)));

static __device__ __forceinline__ unsigned short f2bf(float f) {
    union { float f; unsigned int u; } v; v.f = f;
    unsigned int r = v.u + 0x7FFFu + ((v.u >> 16) & 1u);   // RTNE
    return (unsigned short)(r >> 16);
}
static __device__ __forceinline__ bf8 ld_bf8(const unsigned short* p) {
    return *(const bf8*)p;
}
// gelu with A&S 7.1.26 erf (|err| < 1.5e-7)
static __device__ __forceinline__ float gelu_f(float v) {
    float u = fabsf(v) * 0.70710678118654752f;
    float tt = __builtin_amdgcn_rcpf(1.f + 0.3275911f * u);
    float poly = tt * (0.254829592f + tt * (-0.284496736f + tt * (1.421413741f
               + tt * (-1.453152027f + tt * 1.061405429f))));
    float erfu = 1.f - poly * __expf(-u * u);
    float cdf = 0.5f + 0.5f * (v < 0.f ? -erfu : erfu);
    return v * cdf;
}

// ---------------- K1: per-channel mean/rstd of x over (B,N) ----------------
__global__ void bn1_stats(const float* __restrict__ x, float* __restrict__ bn1) {
    int c = blockIdx.x, t = threadIdx.x;
    float s = 0.f, ss = 0.f;
    for (int i4 = t; i4 < BN_ / 4; i4 += 256) {
        int b = i4 >> 10, n4 = i4 & 1023;
        float4 v = ((const float4*)(x + (b * C + c) * N))[n4];
        s += v.x + v.y + v.z + v.w;
        ss += v.x * v.x + v.y * v.y + v.z * v.z + v.w * v.w;
    }
    __shared__ float rs_[256], rss_[256];
    rs_[t] = s; rss_[t] = ss; __syncthreads();
    for (int w = 128; w > 0; w >>= 1) {
        if (t < w) { rs_[t] += rs_[t + w]; rss_[t] += rss_[t + w]; }
        __syncthreads();
    }
    if (t == 0) {
        float mu = rs_[0] / (float)BN_;
        float var = rss_[0] / (float)BN_ - mu * mu;
        bn1[c] = mu; bn1[3 + c] = rsqrtf(var + EPS);
    }
}

// ---------------- K2: xn4 = (xn_x, xn_y, xn_z, sum xn^2) AoS ----------------
__global__ void compute_xn(const float* __restrict__ x,
                           const float* __restrict__ g1,
                           const float* __restrict__ b1,
                           const float* __restrict__ bn1,
                           float4* __restrict__ xn4) {
    int i = blockIdx.x * 256 + threadIdx.x;
    if (i >= BN_) return;
    int b = i >> 12, n = i & (N - 1);
    float v[3];
    #pragma unroll
    for (int c = 0; c < C; c++)
        v[c] = (x[(b * C + c) * N + n] - bn1[c]) * bn1[3 + c] * g1[c] + b1[c];
    float4 o; o.x = v[0]; o.y = v[1]; o.z = v[2];
    o.w = v[0] * v[0] + v[1] * v[1] + v[2] * v[2];
    xn4[i] = o;
}

// ---------------- K2b: convert W2b / Wf to bf16 ----------------
__global__ void cvt_weights(const float* __restrict__ W2b, const float* __restrict__ Wf,
                            unsigned short* __restrict__ w2b_bf, unsigned short* __restrict__ wf_bf) {
    int i = blockIdx.x * 256 + threadIdx.x;
    if (i < E * E) w2b_bf[i] = f2bf(W2b[i]);
    if (i < E * 2 * E) wf_bf[i] = f2bf(Wf[i]);
}

// ---------------- K3: top-16 (largest d2), one WAVE per point, no barriers ----------------
// Per lane: 64 candidates in registers (constant-indexed only) + 8 chunk maxes.
// Round: 6 value-shfl wave max -> ballot lowest lane -> winner-only chunked rescan.
__global__ void __launch_bounds__(256, 4) knn_kernel(const float4* __restrict__ xn4,
                                                     unsigned short* __restrict__ idxout,
                                                     float* __restrict__ S9) {
    __shared__ float smom[4][15][9];
    int w = threadIdx.x >> 6, lane = threadIdx.x & 63;
    int i = blockIdx.x * 4 + w;
    int b = i >> 12, n = i & (N - 1);
    const float4* xb = xn4 + b * N;
    float4 qv = xb[n];
    float d[64];
    #pragma unroll
    for (int s = 0; s < 64; s++) {
        float4 p = xb[s * 64 + lane];
        d[s] = qv.w + p.w - 2.f * (qv.x * p.x + qv.y * p.y + qv.z * p.z);
    }
    float cm[8];
    #pragma unroll
    for (int c = 0; c < 8; c++) {
        float v = d[c * 8];
        #pragma unroll
        for (int s = 1; s < 8; s++) v = fmaxf(v, d[c * 8 + s]);
        cm[c] = v;
    }
    float bv = cm[0];
    #pragma unroll
    for (int c = 1; c < 8; c++) bv = fmaxf(bv, cm[c]);

    int myj = 0;
    for (int r = 0; r < 16; r++) {
        float wv = bv;
        #pragma unroll
        for (int off = 32; off > 0; off >>= 1)
            wv = fmaxf(wv, __shfl_xor(wv, off));
        unsigned long long msk = __ballot(bv == wv);
        int wl = __ffsll(msk) - 1;
        int gi = 0;
        if (lane == wl) {
            int cstar = 0; bool got = false;
            #pragma unroll
            for (int c = 0; c < 8; c++) {
                bool h = !got && (cm[c] == bv);
                cstar = h ? c : cstar;
                got = got || h;
            }
            int slot = 0;
            #pragma unroll
            for (int c = 0; c < 8; c++) {
                if (c == cstar) {   // 7 of 8 bodies skipped via execz
                    bool g2 = false;
                    #pragma unroll
                    for (int s = 0; s < 8; s++) {
                        bool h = !g2 && (d[c * 8 + s] == bv);
                        slot = h ? (c * 8 + s) : slot;
                        g2 = g2 || h;
                    }
                    #pragma unroll
                    for (int s = 0; s < 8; s++)
                        d[c * 8 + s] = (c * 8 + s == slot) ? -FLT_MAX : d[c * 8 + s];
                    float v = d[c * 8];
                    #pragma unroll
                    for (int s = 1; s < 8; s++) v = fmaxf(v, d[c * 8 + s]);
                    cm[c] = v;
                }
            }
            bv = cm[0];
            #pragma unroll
            for (int c = 1; c < 8; c++) bv = fmaxf(bv, cm[c]);
            gi = slot * 64 + lane;
        }
        int g = __shfl(gi, wl);
        if (lane == r - 1) myj = g;   // lanes 0..14 capture ranks 1..15
    }

    bool act = lane < 15;
    if (act) idxout[i * KNN + lane] = (unsigned short)myj;
    float4 pj = xb[act ? myj : n];
    float v0 = pj.x - qv.x, v1 = pj.y - qv.y, v2 = pj.z - qv.z;
    if (act) {
        float* mm = smom[w][lane];
        mm[0] = v0; mm[1] = v1; mm[2] = v2;
        mm[3] = v0 * v0; mm[4] = v1 * v1; mm[5] = v2 * v2;
        mm[6] = v0 * v1; mm[7] = v0 * v2; mm[8] = v1 * v2;
    }
    __syncthreads();
    int t = threadIdx.x;
    if (t < 36) {
        int wsel = t / 9, j = t % 9;
        float a = 0.f;
        #pragma unroll
        for (int u = 0; u < 15; u++) a += smom[wsel][u][j];
        atomicAdd(&S9[((blockIdx.x * 4 + wsel) & 63) * 9 + j], a);
    }
}

// ---------------- K5: closed-form BN2a affine + per-E BN2b scale/shift ----------------
__global__ void finalize_stats(const float* __restrict__ S9,
                               const float* __restrict__ g2a, const float* __restrict__ b2a,
                               const float* __restrict__ W2a,
                               const float* __restrict__ g2b, const float* __restrict__ b2b,
                               float* __restrict__ ab, float* __restrict__ sc, float* __restrict__ sh) {
    const float cnt = (float)(BN_ * KNN);
    __shared__ float S[9];
    __shared__ float alpha[3], beta[3], mu[3], Ehh[3][3];
    int t = threadIdx.x;
    if (t < 9) {
        float a = 0.f;
        for (int u = 0; u < 64; u++) a += S9[u * 9 + t];
        S[t] = a;
    }
    __syncthreads();
    if (t == 0) {
        float m[3];
        float s2[3][3];
        s2[0][0] = S[3]; s2[1][1] = S[4]; s2[2][2] = S[5];
        s2[0][1] = s2[1][0] = S[6]; s2[0][2] = s2[2][0] = S[7]; s2[1][2] = s2[2][1] = S[8];
        for (int c = 0; c < 3; c++) {
            m[c] = S[c] / cnt;
            float var = s2[c][c] / cnt - m[c] * m[c];
            alpha[c] = g2a[c] * rsqrtf(var + EPS);
            beta[c]  = b2a[c] - m[c] * alpha[c];
            mu[c] = m[c];
            ab[c] = alpha[c]; ab[3 + c] = beta[c];
        }
        for (int c = 0; c < 3; c++)
            for (int cc = 0; cc < 3; cc++)
                Ehh[c][cc] = alpha[c] * alpha[cc] * (s2[c][cc] / cnt)
                           + alpha[c] * beta[cc] * m[c]
                           + beta[c] * alpha[cc] * m[cc]
                           + beta[c] * beta[cc];
    }
    __syncthreads();
    int e = t;
    float wv[3], Eh[3];
    for (int c = 0; c < 3; c++) { wv[c] = W2a[e * 3 + c]; Eh[c] = alpha[c] * mu[c] + beta[c]; }
    float mean = wv[0] * Eh[0] + wv[1] * Eh[1] + wv[2] * Eh[2];
    float m2 = 0.f;
    for (int c = 0; c < 3; c++)
        for (int cc = 0; cc < 3; cc++) m2 += wv[c] * wv[cc] * Ehh[c][cc];
    float var = m2 - mean * mean;
    float s = g2b[e] * rsqrtf(var + EPS);
    sc[e] = s;
    sh[e] = b2b[e] - mean * s;
}

// ---------------- K6: fused W2a→BN2b→gelu→[MFMA W2b]→max | point_emb | [MFMA Wf] ----------------
// Phase C uses A=hh, B=w2b so k lands on D ROWS: max = 3 fmax + 2 shfl per tile.
__global__ void __launch_bounds__(256, 3) fused_final(
        const float4* __restrict__ xn4, const unsigned short* __restrict__ idx,
        const float* __restrict__ ab,
        const float* __restrict__ W2a,
        const float* __restrict__ sc, const float* __restrict__ sh,
        const unsigned short* __restrict__ w2b_bf,
        const float* __restrict__ W1, const float* __restrict__ bw1,
        const unsigned short* __restrict__ wf_bf, const float* __restrict__ bfv,
        float* __restrict__ out) {
    __shared__ __align__(16) unsigned short hh_bf[64 * SR];    // row n=16p+k, col e (bf16)
    __shared__ __align__(16) unsigned short feat_bf[4 * SRF];  // row p, col f 0..511 (bf16)
    __shared__ float hhat[P][3][16];
    int i0 = blockIdx.x * P;
    int t = threadIdx.x;
    int b = i0 >> 12, n0 = i0 & (N - 1);
    const float4* xb = xn4 + b * N;

    if (t < P * KNN) {   // phase A: gather + BN2a affine
        int p = t / KNN, k = t % KNN;
        int j = idx[(i0 + p) * KNN + k];
        float4 pj = xb[j];
        float4 pn = xb[n0 + p];
        hhat[p][0][k] = ab[0] * (pj.x - pn.x) + ab[3];
        hhat[p][1][k] = ab[1] * (pj.y - pn.y) + ab[4];
        hhat[p][2][k] = ab[2] * (pj.z - pn.z) + ab[5];
    }
    __syncthreads();

    {   // phase B: h = W2a @ hhat, BN2b affine, gelu (bf16 to LDS); point_emb
        int e = t;
        float w0 = W2a[e * 3], w1 = W2a[e * 3 + 1], w2 = W2a[e * 3 + 2];
        float s = sc[e], o = sh[e];
        #pragma unroll
        for (int p = 0; p < P; p++) {
            float g0 = 0.f;
            #pragma unroll
            for (int k = 0; k < KNN; k++) {
                float v = s * (w0 * hhat[p][0][k] + w1 * hhat[p][1][k] + w2 * hhat[p][2][k]) + o;
                float g = gelu_f(v);
                hh_bf[(16 * p + k) * SR + e] = f2bf(g);
                if (k == 0) g0 = g;
            }
            hh_bf[(16 * p + 15) * SR + e] = f2bf(g0);   // dup row: max unaffected
            float4 pv = xb[n0 + p];
            feat_bf[p * SRF + e] = f2bf(bw1[e] + W1[e * 3] * pv.x
                       + W1[e * 3 + 1] * pv.y + W1[e * 3 + 2] * pv.z);
        }
    }
    __syncthreads();

    int w = t >> 6, lane = t & 63;
    int m = lane & 15, q = lane >> 4;

    {   // phase C: D[k][f] = hh^T-tile x w2b-tile; max over k-rows -> feat_bf[:,256:512]
        int fh = w >> 1, pp = w & 1;
        bf8 hfr[2][8];
        #pragma unroll
        for (int pi = 0; pi < 2; pi++)
            #pragma unroll
            for (int kb = 0; kb < 8; kb++)
                hfr[pi][kb] = ld_bf8(&hh_bf[(16 * (pp * 2 + pi) + m) * SR + kb * 32 + q * 8]);

        auto mfma_step = [&](const bf8* cw, int ft) {
            #pragma unroll
            for (int pi = 0; pi < 2; pi++) {
                f4 acc = {0.f, 0.f, 0.f, 0.f};
                #pragma unroll
                for (int kb = 0; kb < 8; kb++)
                    acc = __builtin_amdgcn_mfma_f32_16x16x32_bf16(hfr[pi][kb], cw[kb], acc, 0, 0, 0);
                float mx = fmaxf(fmaxf(acc[0], acc[1]), fmaxf(acc[2], acc[3]));
                mx = fmaxf(mx, __shfl_xor(mx, 16));
                mx = fmaxf(mx, __shfl_xor(mx, 32));
                if (lane < 16)
                    feat_bf[(pp * 2 + pi) * SRF + E + (fh * 8 + ft) * 16 + lane] = f2bf(mx);
            }
        };

        bf8 wt0[8], wt1[8];
        #pragma unroll
        for (int kb = 0; kb < 8; kb++)
            wt0[kb] = ld_bf8(&w2b_bf[(fh * 128 + m) * 256 + kb * 32 + q * 8]);
        #pragma unroll
        for (int fp = 0; fp < 4; fp++) {
            int ft0 = fp * 2, ft1 = fp * 2 + 1;
            #pragma unroll
            for (int kb = 0; kb < 8; kb++)
                wt1[kb] = ld_bf8(&w2b_bf[((fh * 8 + ft1) * 16 + m) * 256 + kb * 32 + q * 8]);
            mfma_step(wt0, ft0);
            if (fp < 3) {
                #pragma unroll
                for (int kb = 0; kb < 8; kb++)
                    wt0[kb] = ld_bf8(&w2b_bf[((fh * 8 + ft1 + 1) * 16 + m) * 256 + kb * 32 + q * 8]);
            }
            mfma_step(wt1, ft1);
        }
    }
    __syncthreads();

    {   // phase D: out = Wf @ feat^T via MFMA (cols = points; feat fragments hoisted)
        bf8 fb[16];
        #pragma unroll
        for (int kb = 0; kb < 16; kb++)
            fb[kb] = ld_bf8(&feat_bf[(m & 3) * SRF + kb * 32 + q * 8]);
        #pragma unroll
        for (int ot = 0; ot < 4; ot++) {
            int obase = (w * 4 + ot) * 16;
            f4 acc = {0.f, 0.f, 0.f, 0.f};
            #pragma unroll
            for (int kb = 0; kb < 16; kb++) {
                bf8 a = ld_bf8(&wf_bf[(obase + m) * 512 + kb * 32 + q * 8]);
                acc = __builtin_amdgcn_mfma_f32_16x16x32_bf16(a, fb[kb], acc, 0, 0, 0);
            }
            if (m < P) {   // col = m = point; row = obase + 4q + reg
                int o0 = obase + 4 * q;
                out[(b * E + o0 + 0) * N + n0 + m] = acc[0] + bfv[o0 + 0];
                out[(b * E + o0 + 1) * N + n0 + m] = acc[1] + bfv[o0 + 1];
                out[(b * E + o0 + 2) * N + n0 + m] = acc[2] + bfv[o0 + 2];
                out[(b * E + o0 + 3) * N + n0 + m] = acc[3] + bfv[o0 + 3];
            }
        }
    }
}

extern "C" void kernel_launch(void* const* d_in, const int* in_sizes, int n_in,
                              void* d_out, int out_size, void* d_ws, size_t ws_size,
                              hipStream_t stream) {
    (void)in_sizes; (void)n_in; (void)out_size; (void)ws_size;
    const float* x   = (const float*)d_in[0];
    const float* g1  = (const float*)d_in[1];
    const float* b1  = (const float*)d_in[2];
    const float* W1  = (const float*)d_in[3];
    const float* bw1 = (const float*)d_in[4];
    const float* g2a = (const float*)d_in[5];
    const float* b2a = (const float*)d_in[6];
    const float* W2a = (const float*)d_in[7];
    const float* g2b = (const float*)d_in[8];
    const float* b2b = (const float*)d_in[9];
    const float* W2b = (const float*)d_in[10];
    const float* Wf  = (const float*)d_in[11];
    const float* bfv = (const float*)d_in[12];
    float* out = (float*)d_out;

    char* ws = (char*)d_ws;
    size_t off = 0;
    auto alloc = [&](size_t bytes) { size_t o = off; off = (off + bytes + 255) & ~(size_t)255; return o; };
    float4* xn4           = (float4*)(ws + alloc(sizeof(float4) * BN_));
    unsigned short* idx   = (unsigned short*)(ws + alloc(sizeof(unsigned short) * BN_ * KNN));
    float* bn1            = (float*)(ws + alloc(sizeof(float) * 8));
    float* S9             = (float*)(ws + alloc(sizeof(float) * 64 * 9));
    float* ab             = (float*)(ws + alloc(sizeof(float) * 8));
    float* sc             = (float*)(ws + alloc(sizeof(float) * E));
    float* sh             = (float*)(ws + alloc(sizeof(float) * E));
    unsigned short* w2bbf = (unsigned short*)(ws + alloc(sizeof(unsigned short) * E * E));
    unsigned short* wfbf  = (unsigned short*)(ws + alloc(sizeof(unsigned short) * E * 2 * E));

    hipMemsetAsync(S9, 0, sizeof(float) * 64 * 9, stream);

    bn1_stats<<<C, 256, 0, stream>>>(x, bn1);
    compute_xn<<<BN_ / 256, 256, 0, stream>>>(x, g1, b1, bn1, xn4);
    cvt_weights<<<(E * 2 * E) / 256, 256, 0, stream>>>(W2b, Wf, w2bbf, wfbf);
    knn_kernel<<<BN_ / 4, 256, 0, stream>>>(xn4, idx, S9);
    finalize_stats<<<1, 256, 0, stream>>>(S9, g2a, b2a, W2a, g2b, b2b, ab, sc, sh);
    fused_final<<<BN_ / P, 256, 0, stream>>>(xn4, idx, ab, W2a, sc, sh, w2bbf, W1, bw1, wfbf, bfv, out);
}

// Round 6
// 412.064 us; speedup vs baseline: 3.4524x; 1.0277x over previous
//
#include <hip/hip_runtime.h>
#include <float.h>
#include <math.h>

#define EPS 1e-5f
constexpr int B = 4, C = 3, N = 4096, E = 256;
constexpr int KNN = 15;            // 15 neighbors kept (top-16 minus rank 0)
constexpr int BN_ = B * N;         // 16384
constexpr int P = 4;               // points per block in fused kernel
constexpr int SR  = 264;           // hh_bf row stride (ushorts)
constexpr int SRF = 520;           // feat_bf row stride (ushorts)

typedef short bf8 __attribute__((ext_vector_type(8)));   // 8 bf16 in 4 VGPRs
typedef float f4  __attribute__((ext_vector_type(4)));

static __device__ __forceinline__ unsigned short f2bf(float f) {
    union { float f; unsigned int u; } v; v.f = f;
    unsigned int r = v.u + 0x7FFFu + ((v.u >> 16) & 1u);   // RTNE
    return (unsigned short)(r >> 16);
}
static __device__ __forceinline__ bf8 ld_bf8(const unsigned short* p) {
    return *(const bf8*)p;
}
// gelu with A&S 7.1.26 erf (|err| < 1.5e-7)
static __device__ __forceinline__ float gelu_f(float v) {
    float u = fabsf(v) * 0.70710678118654752f;
    float tt = __builtin_amdgcn_rcpf(1.f + 0.3275911f * u);
    float poly = tt * (0.254829592f + tt * (-0.284496736f + tt * (1.421413741f
               + tt * (-1.453152027f + tt * 1.061405429f))));
    float erfu = 1.f - poly * __expf(-u * u);
    float cdf = 0.5f + 0.5f * (v < 0.f ? -erfu : erfu);
    return v * cdf;
}

// ---------------- K1: per-channel mean/rstd of x over (B,N) ----------------
__global__ void bn1_stats(const float* __restrict__ x, float* __restrict__ bn1) {
    int c = blockIdx.x, t = threadIdx.x;
    float s = 0.f, ss = 0.f;
    for (int i4 = t; i4 < BN_ / 4; i4 += 256) {
        int b = i4 >> 10, n4 = i4 & 1023;
        float4 v = ((const float4*)(x + (b * C + c) * N))[n4];
        s += v.x + v.y + v.z + v.w;
        ss += v.x * v.x + v.y * v.y + v.z * v.z + v.w * v.w;
    }
    __shared__ float rs_[256], rss_[256];
    rs_[t] = s; rss_[t] = ss; __syncthreads();
    for (int w = 128; w > 0; w >>= 1) {
        if (t < w) { rs_[t] += rs_[t + w]; rss_[t] += rss_[t + w]; }
        __syncthreads();
    }
    if (t == 0) {
        float mu = rs_[0] / (float)BN_;
        float var = rss_[0] / (float)BN_ - mu * mu;
        bn1[c] = mu; bn1[3 + c] = rsqrtf(var + EPS);
    }
}

// ---------------- K2: xn4 AoS (blocks 0..63) + weight bf16 convert (blocks 64..575) ----------------
__global__ void compute_xn_cvt(const float* __restrict__ x,
                               const float* __restrict__ g1,
                               const float* __restrict__ b1,
                               const float* __restrict__ bn1,
                               float4* __restrict__ xn4,
                               const float* __restrict__ W2b, const float* __restrict__ Wf,
                               unsigned short* __restrict__ w2b_bf, unsigned short* __restrict__ wf_bf) {
    int blk = blockIdx.x;
    if (blk < BN_ / 256) {
        int i = blk * 256 + threadIdx.x;
        int b = i >> 12, n = i & (N - 1);
        float v[3];
        #pragma unroll
        for (int c = 0; c < C; c++)
            v[c] = (x[(b * C + c) * N + n] - bn1[c]) * bn1[3 + c] * g1[c] + b1[c];
        float4 o; o.x = v[0]; o.y = v[1]; o.z = v[2];
        o.w = v[0] * v[0] + v[1] * v[1] + v[2] * v[2];
        xn4[i] = o;
    } else {
        int i = (blk - BN_ / 256) * 256 + threadIdx.x;
        if (i < E * E) w2b_bf[i] = f2bf(W2b[i]);
        wf_bf[i] = f2bf(Wf[i]);
    }
}

// ---------------- K3: top-16 (largest d2), one WAVE per point, no barriers ----------------
__global__ void __launch_bounds__(256, 4) knn_kernel(const float4* __restrict__ xn4,
                                                     unsigned short* __restrict__ idxout,
                                                     float* __restrict__ S9) {
    __shared__ float smom[4][15][9];
    int w = threadIdx.x >> 6, lane = threadIdx.x & 63;
    int i = blockIdx.x * 4 + w;
    int b = i >> 12, n = i & (N - 1);
    const float4* xb = xn4 + b * N;
    float4 qv = xb[n];
    float d[64];
    #pragma unroll
    for (int s = 0; s < 64; s++) {
        float4 p = xb[s * 64 + lane];
        d[s] = qv.w + p.w - 2.f * (qv.x * p.x + qv.y * p.y + qv.z * p.z);
    }
    float cm[8];
    #pragma unroll
    for (int c = 0; c < 8; c++) {
        float v = d[c * 8];
        #pragma unroll
        for (int s = 1; s < 8; s++) v = fmaxf(v, d[c * 8 + s]);
        cm[c] = v;
    }
    float bv = cm[0];
    #pragma unroll
    for (int c = 1; c < 8; c++) bv = fmaxf(bv, cm[c]);

    int myj = 0;
    for (int r = 0; r < 16; r++) {
        float wv = bv;
        #pragma unroll
        for (int off = 32; off > 0; off >>= 1)
            wv = fmaxf(wv, __shfl_xor(wv, off));
        unsigned long long msk = __ballot(bv == wv);
        int wl = __ffsll(msk) - 1;
        int gi = 0;
        if (lane == wl) {
            int cstar = 0; bool got = false;
            #pragma unroll
            for (int c = 0; c < 8; c++) {
                bool h = !got && (cm[c] == bv);
                cstar = h ? c : cstar;
                got = got || h;
            }
            int slot = 0;
            #pragma unroll
            for (int c = 0; c < 8; c++) {
                if (c == cstar) {   // 7 of 8 bodies skipped via execz
                    bool g2 = false;
                    #pragma unroll
                    for (int s = 0; s < 8; s++) {
                        bool h = !g2 && (d[c * 8 + s] == bv);
                        slot = h ? (c * 8 + s) : slot;
                        g2 = g2 || h;
                    }
                    #pragma unroll
                    for (int s = 0; s < 8; s++)
                        d[c * 8 + s] = (c * 8 + s == slot) ? -FLT_MAX : d[c * 8 + s];
                    float v = d[c * 8];
                    #pragma unroll
                    for (int s = 1; s < 8; s++) v = fmaxf(v, d[c * 8 + s]);
                    cm[c] = v;
                }
            }
            bv = cm[0];
            #pragma unroll
            for (int c = 1; c < 8; c++) bv = fmaxf(bv, cm[c]);
            gi = slot * 64 + lane;
        }
        int g = __shfl(gi, wl);
        if (lane == r - 1) myj = g;   // lanes 0..14 capture ranks 1..15
    }

    bool act = lane < 15;
    if (act) idxout[i * KNN + lane] = (unsigned short)myj;
    float4 pj = xb[act ? myj : n];
    float v0 = pj.x - qv.x, v1 = pj.y - qv.y, v2 = pj.z - qv.z;
    if (act) {
        float* mm = smom[w][lane];
        mm[0] = v0; mm[1] = v1; mm[2] = v2;
        mm[3] = v0 * v0; mm[4] = v1 * v1; mm[5] = v2 * v2;
        mm[6] = v0 * v1; mm[7] = v0 * v2; mm[8] = v1 * v2;
    }
    __syncthreads();
    int t = threadIdx.x;
    if (t < 36) {
        int wsel = t / 9, j = t % 9;
        float a = 0.f;
        #pragma unroll
        for (int u = 0; u < 15; u++) a += smom[wsel][u][j];
        atomicAdd(&S9[((blockIdx.x * 4 + wsel) & 63) * 9 + j], a);
    }
}

// ---------------- K5: closed-form BN2a affine + per-E BN2b scale/shift ----------------
__global__ void finalize_stats(const float* __restrict__ S9,
                               const float* __restrict__ g2a, const float* __restrict__ b2a,
                               const float* __restrict__ W2a,
                               const float* __restrict__ g2b, const float* __restrict__ b2b,
                               float* __restrict__ ab, float* __restrict__ sc, float* __restrict__ sh) {
    const float cnt = (float)(BN_ * KNN);
    __shared__ float S[9];
    __shared__ float alpha[3], beta[3], mu[3], Ehh[3][3];
    int t = threadIdx.x;
    if (t < 9) {
        float a = 0.f;
        for (int u = 0; u < 64; u++) a += S9[u * 9 + t];
        S[t] = a;
    }
    __syncthreads();
    if (t == 0) {
        float m[3];
        float s2[3][3];
        s2[0][0] = S[3]; s2[1][1] = S[4]; s2[2][2] = S[5];
        s2[0][1] = s2[1][0] = S[6]; s2[0][2] = s2[2][0] = S[7]; s2[1][2] = s2[2][1] = S[8];
        for (int c = 0; c < 3; c++) {
            m[c] = S[c] / cnt;
            float var = s2[c][c] / cnt - m[c] * m[c];
            alpha[c] = g2a[c] * rsqrtf(var + EPS);
            beta[c]  = b2a[c] - m[c] * alpha[c];
            mu[c] = m[c];
            ab[c] = alpha[c]; ab[3 + c] = beta[c];
        }
        for (int c = 0; c < 3; c++)
            for (int cc = 0; cc < 3; cc++)
                Ehh[c][cc] = alpha[c] * alpha[cc] * (s2[c][cc] / cnt)
                           + alpha[c] * beta[cc] * m[c]
                           + beta[c] * alpha[cc] * m[cc]
                           + beta[c] * beta[cc];
    }
    __syncthreads();
    int e = t;
    float wv[3], Eh[3];
    for (int c = 0; c < 3; c++) { wv[c] = W2a[e * 3 + c]; Eh[c] = alpha[c] * mu[c] + beta[c]; }
    float mean = wv[0] * Eh[0] + wv[1] * Eh[1] + wv[2] * Eh[2];
    float m2 = 0.f;
    for (int c = 0; c < 3; c++)
        for (int cc = 0; cc < 3; cc++) m2 += wv[c] * wv[cc] * Ehh[c][cc];
    float var = m2 - mean * mean;
    float s = g2b[e] * rsqrtf(var + EPS);
    sc[e] = s;
    sh[e] = b2b[e] - mean * s;
}

// ---------------- K6: fused W2a→BN2b→gelu→[MFMA W2b]→max | point_emb | [MFMA Wf] ----------------
// Phase C: A=hh, B=w2b so k lands on D ROWS: max = 3 fmax + 2 shfl per tile.
// Simple per-ft load->mfma structure: let the compiler software-pipeline (R5's
// manual double-buffer regressed 265->293 us by defeating its scheduling).
__global__ void __launch_bounds__(256, 4) fused_final(
        const float4* __restrict__ xn4, const unsigned short* __restrict__ idx,
        const float* __restrict__ ab,
        const float* __restrict__ W2a,
        const float* __restrict__ sc, const float* __restrict__ sh,
        const unsigned short* __restrict__ w2b_bf,
        const float* __restrict__ W1, const float* __restrict__ bw1,
        const unsigned short* __restrict__ wf_bf, const float* __restrict__ bfv,
        float* __restrict__ out) {
    __shared__ __align__(16) unsigned short hh_bf[64 * SR];    // row n=16p+k, col e (bf16)
    __shared__ __align__(16) unsigned short feat_bf[4 * SRF];  // row p, col f 0..511 (bf16)
    __shared__ float hhat[P][3][16];
    int i0 = blockIdx.x * P;
    int t = threadIdx.x;
    int b = i0 >> 12, n0 = i0 & (N - 1);
    const float4* xb = xn4 + b * N;

    if (t < P * KNN) {   // phase A: gather + BN2a affine
        int p = t / KNN, k = t % KNN;
        int j = idx[(i0 + p) * KNN + k];
        float4 pj = xb[j];
        float4 pn = xb[n0 + p];
        hhat[p][0][k] = ab[0] * (pj.x - pn.x) + ab[3];
        hhat[p][1][k] = ab[1] * (pj.y - pn.y) + ab[4];
        hhat[p][2][k] = ab[2] * (pj.z - pn.z) + ab[5];
    }
    __syncthreads();

    {   // phase B: h = W2a @ hhat, BN2b affine, gelu (bf16 to LDS); point_emb
        int e = t;
        float w0 = W2a[e * 3], w1 = W2a[e * 3 + 1], w2 = W2a[e * 3 + 2];
        float s = sc[e], o = sh[e];
        #pragma unroll
        for (int p = 0; p < P; p++) {
            float g0 = 0.f;
            #pragma unroll
            for (int k = 0; k < KNN; k++) {
                float v = s * (w0 * hhat[p][0][k] + w1 * hhat[p][1][k] + w2 * hhat[p][2][k]) + o;
                float g = gelu_f(v);
                hh_bf[(16 * p + k) * SR + e] = f2bf(g);
                if (k == 0) g0 = g;
            }
            hh_bf[(16 * p + 15) * SR + e] = f2bf(g0);   // dup row: max unaffected
            float4 pv = xb[n0 + p];
            feat_bf[p * SRF + e] = f2bf(bw1[e] + W1[e * 3] * pv.x
                       + W1[e * 3 + 1] * pv.y + W1[e * 3 + 2] * pv.z);
        }
    }
    __syncthreads();

    int w = t >> 6, lane = t & 63;
    int m = lane & 15, q = lane >> 4;

    {   // phase C: D[k][f] = hh-tile x w2b-tile; max over k-rows -> feat_bf[:,256:512]
        int fh = w >> 1, pp = w & 1;
        bf8 hfr[2][8];
        #pragma unroll
        for (int pi = 0; pi < 2; pi++)
            #pragma unroll
            for (int kb = 0; kb < 8; kb++)
                hfr[pi][kb] = ld_bf8(&hh_bf[(16 * (pp * 2 + pi) + m) * SR + kb * 32 + q * 8]);

        for (int ft = 0; ft < 8; ft++) {
            int fbase = (fh * 8 + ft) * 16;
            bf8 a[8];
            #pragma unroll
            for (int kb = 0; kb < 8; kb++)
                a[kb] = ld_bf8(&w2b_bf[(fbase + m) * 256 + kb * 32 + q * 8]);
            #pragma unroll
            for (int pi = 0; pi < 2; pi++) {
                f4 acc = {0.f, 0.f, 0.f, 0.f};
                #pragma unroll
                for (int kb = 0; kb < 8; kb++)
                    acc = __builtin_amdgcn_mfma_f32_16x16x32_bf16(hfr[pi][kb], a[kb], acc, 0, 0, 0);
                float mx = fmaxf(fmaxf(acc[0], acc[1]), fmaxf(acc[2], acc[3]));
                mx = fmaxf(mx, __shfl_xor(mx, 16));
                mx = fmaxf(mx, __shfl_xor(mx, 32));
                if (lane < 16)
                    feat_bf[(pp * 2 + pi) * SRF + E + fbase + lane] = f2bf(mx);
            }
        }
    }
    __syncthreads();

    {   // phase D: out = Wf @ feat^T via MFMA (cols = points; feat fragments hoisted)
        bf8 fb[16];
        #pragma unroll
        for (int kb = 0; kb < 16; kb++)
            fb[kb] = ld_bf8(&feat_bf[(m & 3) * SRF + kb * 32 + q * 8]);
        #pragma unroll
        for (int ot = 0; ot < 4; ot++) {
            int obase = (w * 4 + ot) * 16;
            f4 acc = {0.f, 0.f, 0.f, 0.f};
            #pragma unroll
            for (int kb = 0; kb < 16; kb++) {
                bf8 a = ld_bf8(&wf_bf[(obase + m) * 512 + kb * 32 + q * 8]);
                acc = __builtin_amdgcn_mfma_f32_16x16x32_bf16(a, fb[kb], acc, 0, 0, 0);
            }
            if (m < P) {   // col = m = point; row = obase + 4q + reg
                int o0 = obase + 4 * q;
                out[(b * E + o0 + 0) * N + n0 + m] = acc[0] + bfv[o0 + 0];
                out[(b * E + o0 + 1) * N + n0 + m] = acc[1] + bfv[o0 + 1];
                out[(b * E + o0 + 2) * N + n0 + m] = acc[2] + bfv[o0 + 2];
                out[(b * E + o0 + 3) * N + n0 + m] = acc[3] + bfv[o0 + 3];
            }
        }
    }
}

extern "C" void kernel_launch(void* const* d_in, const int* in_sizes, int n_in,
                              void* d_out, int out_size, void* d_ws, size_t ws_size,
                              hipStream_t stream) {
    (void)in_sizes; (void)n_in; (void)out_size; (void)ws_size;
    const float* x   = (const float*)d_in[0];
    const float* g1  = (const float*)d_in[1];
    const float* b1  = (const float*)d_in[2];
    const float* W1  = (const float*)d_in[3];
    const float* bw1 = (const float*)d_in[4];
    const float* g2a = (const float*)d_in[5];
    const float* b2a = (const float*)d_in[6];
    const float* W2a = (const float*)d_in[7];
    const float* g2b = (const float*)d_in[8];
    const float* b2b = (const float*)d_in[9];
    const float* W2b = (const float*)d_in[10];
    const float* Wf  = (const float*)d_in[11];
    const float* bfv = (const float*)d_in[12];
    float* out = (float*)d_out;

    char* ws = (char*)d_ws;
    size_t off = 0;
    auto alloc = [&](size_t bytes) { size_t o = off; off = (off + bytes + 255) & ~(size_t)255; return o; };
    float4* xn4           = (float4*)(ws + alloc(sizeof(float4) * BN_));
    unsigned short* idx   = (unsigned short*)(ws + alloc(sizeof(unsigned short) * BN_ * KNN));
    float* bn1            = (float*)(ws + alloc(sizeof(float) * 8));
    float* S9             = (float*)(ws + alloc(sizeof(float) * 64 * 9));
    float* ab             = (float*)(ws + alloc(sizeof(float) * 8));
    float* sc             = (float*)(ws + alloc(sizeof(float) * E));
    float* sh             = (float*)(ws + alloc(sizeof(float) * E));
    unsigned short* w2bbf = (unsigned short*)(ws + alloc(sizeof(unsigned short) * E * E));
    unsigned short* wfbf  = (unsigned short*)(ws + alloc(sizeof(unsigned short) * E * 2 * E));

    hipMemsetAsync(S9, 0, sizeof(float) * 64 * 9, stream);

    bn1_stats<<<C, 256, 0, stream>>>(x, bn1);
    compute_xn_cvt<<<BN_ / 256 + (E * 2 * E) / 256, 256, 0, stream>>>(
        x, g1, b1, bn1, xn4, W2b, Wf, w2bbf, wfbf);
    knn_kernel<<<BN_ / 4, 256, 0, stream>>>(xn4, idx, S9);
    finalize_stats<<<1, 256, 0, stream>>>(S9, g2a, b2a, W2a, g2b, b2b, ab, sc, sh);
    fused_final<<<BN_ / P, 256, 0, stream>>>(xn4, idx, ab, W2a, sc, sh, w2bbf, W1, bw1, wfbf, bfv, out);
}

// Round 8
// 271.713 us; speedup vs baseline: 5.2357x; 1.5165x over previous
//
#include <hip/hip_runtime.h>
#include <float.h>
#include <math.h>

#define EPS 1e-5f
constexpr int B = 4, C = 3, N = 4096, E = 256;
constexpr int KNN = 15;            // 15 neighbors kept (top-16 minus rank 0)
constexpr int BN_ = B * N;         // 16384
constexpr int P = 4;               // points per block in fused kernel
constexpr int SR  = 264;           // hh_bf row stride (ushorts)
constexpr int SRF = 520;           // feat_bf row stride (ushorts)

typedef short bf8 __attribute__((ext_vector_type(8)));   // 8 bf16 in 4 VGPRs
typedef float f4  __attribute__((ext_vector_type(4)));

static __device__ __forceinline__ unsigned short f2bf(float f) {
    union { float f; unsigned int u; } v; v.f = f;
    unsigned int r = v.u + 0x7FFFu + ((v.u >> 16) & 1u);   // RTNE
    return (unsigned short)(r >> 16);
}
static __device__ __forceinline__ bf8 ld_bf8(const unsigned short* p) {
    return *(const bf8*)p;
}
// gelu with A&S 7.1.26 erf (|err| < 1.5e-7)
static __device__ __forceinline__ float gelu_f(float v) {
    float u = fabsf(v) * 0.70710678118654752f;
    float tt = __builtin_amdgcn_rcpf(1.f + 0.3275911f * u);
    float poly = tt * (0.254829592f + tt * (-0.284496736f + tt * (1.421413741f
               + tt * (-1.453152027f + tt * 1.061405429f))));
    float erfu = 1.f - poly * __expf(-u * u);
    float cdf = 0.5f + 0.5f * (v < 0.f ? -erfu : erfu);
    return v * cdf;
}

// ---------------- K1: per-channel mean/rstd of x over (B,N) ----------------
__global__ void bn1_stats(const float* __restrict__ x, float* __restrict__ bn1) {
    int c = blockIdx.x, t = threadIdx.x;
    float s = 0.f, ss = 0.f;
    for (int i4 = t; i4 < BN_ / 4; i4 += 256) {
        int b = i4 >> 10, n4 = i4 & 1023;
        float4 v = ((const float4*)(x + (b * C + c) * N))[n4];
        s += v.x + v.y + v.z + v.w;
        ss += v.x * v.x + v.y * v.y + v.z * v.z + v.w * v.w;
    }
    __shared__ float rs_[256], rss_[256];
    rs_[t] = s; rss_[t] = ss; __syncthreads();
    for (int w = 128; w > 0; w >>= 1) {
        if (t < w) { rs_[t] += rs_[t + w]; rss_[t] += rss_[t + w]; }
        __syncthreads();
    }
    if (t == 0) {
        float mu = rs_[0] / (float)BN_;
        float var = rss_[0] / (float)BN_ - mu * mu;
        bn1[c] = mu; bn1[3 + c] = rsqrtf(var + EPS);
    }
}

// ---------------- K2: xn4 AoS (blocks 0..63) + tile-lane-major bf16 weights ----------------
// w2b_t: chunk (ft16*8+kb)*64+lane holds W2b[ft16*16+(lane&15)][kb*32+(lane>>4)*8 ..+8]
//        -> ft16-stride 4096 ushorts, kb-stride 512, lane-stride 8 (fully coalesced loads)
// wf_t : chunk (ot*16+kb)*64+lane holds Wf[ot*16+(lane&15)][kb*32+(lane>>4)*8 ..+8]
//        -> ot-stride 8192 ushorts, kb-stride 512, lane-stride 8
__global__ void compute_xn_cvt(const float* __restrict__ x,
                               const float* __restrict__ g1,
                               const float* __restrict__ b1,
                               const float* __restrict__ bn1,
                               float4* __restrict__ xn4,
                               const float* __restrict__ W2b, const float* __restrict__ Wf,
                               unsigned short* __restrict__ w2b_t, unsigned short* __restrict__ wf_t) {
    int blk = blockIdx.x;
    if (blk < BN_ / 256) {
        int i = blk * 256 + threadIdx.x;
        int b = i >> 12, n = i & (N - 1);
        float v[3];
        #pragma unroll
        for (int c = 0; c < C; c++)
            v[c] = (x[(b * C + c) * N + n] - bn1[c]) * bn1[3 + c] * g1[c] + b1[c];
        float4 o; o.x = v[0]; o.y = v[1]; o.z = v[2];
        o.w = v[0] * v[0] + v[1] * v[1] + v[2] * v[2];
        xn4[i] = o;
        return;
    }
    int ch = (blk - BN_ / 256) * 256 + threadIdx.x;   // chunk id (8 bf16 per chunk)
    if (ch < 8192) {               // w2b: 65536 elems = 8192 chunks
        int lane = ch & 63, kb = (ch >> 6) & 7, ft16 = ch >> 9;
        int row = ft16 * 16 + (lane & 15);
        int col = kb * 32 + (lane >> 4) * 8;
        #pragma unroll
        for (int j = 0; j < 8; j++)
            w2b_t[ch * 8 + j] = f2bf(W2b[row * 256 + col + j]);
    } else {                       // wf: 131072 elems = 16384 chunks
        int c2 = ch - 8192;
        int lane = c2 & 63, kb = (c2 >> 6) & 15, ot = c2 >> 10;
        int row = ot * 16 + (lane & 15);
        int col = kb * 32 + (lane >> 4) * 8;
        #pragma unroll
        for (int j = 0; j < 8; j++)
            wf_t[c2 * 8 + j] = f2bf(Wf[row * 512 + col + j]);
    }
}

// ---------------- K3: top-16 (largest d2), one WAVE per point, no barriers ----------------
__global__ void __launch_bounds__(256, 4) knn_kernel(const float4* __restrict__ xn4,
                                                     unsigned short* __restrict__ idxout,
                                                     float* __restrict__ S9) {
    __shared__ float smom[4][15][9];
    int w = threadIdx.x >> 6, lane = threadIdx.x & 63;
    int i = blockIdx.x * 4 + w;
    int b = i >> 12, n = i & (N - 1);
    const float4* xb = xn4 + b * N;
    float4 qv = xb[n];
    float d[64];
    #pragma unroll
    for (int s = 0; s < 64; s++) {
        float4 p = xb[s * 64 + lane];
        d[s] = qv.w + p.w - 2.f * (qv.x * p.x + qv.y * p.y + qv.z * p.z);
    }
    float cm[8];
    #pragma unroll
    for (int c = 0; c < 8; c++) {
        float v = d[c * 8];
        #pragma unroll
        for (int s = 1; s < 8; s++) v = fmaxf(v, d[c * 8 + s]);
        cm[c] = v;
    }
    float bv = cm[0];
    #pragma unroll
    for (int c = 1; c < 8; c++) bv = fmaxf(bv, cm[c]);

    int myj = 0;
    for (int r = 0; r < 16; r++) {
        float wv = bv;
        #pragma unroll
        for (int off = 32; off > 0; off >>= 1)
            wv = fmaxf(wv, __shfl_xor(wv, off));
        unsigned long long msk = __ballot(bv == wv);
        int wl = __ffsll(msk) - 1;
        int gi = 0;
        if (lane == wl) {
            int cstar = 0; bool got = false;
            #pragma unroll
            for (int c = 0; c < 8; c++) {
                bool h = !got && (cm[c] == bv);
                cstar = h ? c : cstar;
                got = got || h;
            }
            int slot = 0;
            #pragma unroll
            for (int c = 0; c < 8; c++) {
                if (c == cstar) {   // 7 of 8 bodies skipped via execz
                    bool g2 = false;
                    #pragma unroll
                    for (int s = 0; s < 8; s++) {
                        bool h = !g2 && (d[c * 8 + s] == bv);
                        slot = h ? (c * 8 + s) : slot;
                        g2 = g2 || h;
                    }
                    #pragma unroll
                    for (int s = 0; s < 8; s++)
                        d[c * 8 + s] = (c * 8 + s == slot) ? -FLT_MAX : d[c * 8 + s];
                    float v = d[c * 8];
                    #pragma unroll
                    for (int s = 1; s < 8; s++) v = fmaxf(v, d[c * 8 + s]);
                    cm[c] = v;
                }
            }
            bv = cm[0];
            #pragma unroll
            for (int c = 1; c < 8; c++) bv = fmaxf(bv, cm[c]);
            gi = slot * 64 + lane;
        }
        int g = __shfl(gi, wl);
        if (lane == r - 1) myj = g;   // lanes 0..14 capture ranks 1..15
    }

    bool act = lane < 15;
    if (act) idxout[i * KNN + lane] = (unsigned short)myj;
    float4 pj = xb[act ? myj : n];
    float v0 = pj.x - qv.x, v1 = pj.y - qv.y, v2 = pj.z - qv.z;
    if (act) {
        float* mm = smom[w][lane];
        mm[0] = v0; mm[1] = v1; mm[2] = v2;
        mm[3] = v0 * v0; mm[4] = v1 * v1; mm[5] = v2 * v2;
        mm[6] = v0 * v1; mm[7] = v0 * v2; mm[8] = v1 * v2;
    }
    __syncthreads();
    int t = threadIdx.x;
    if (t < 36) {
        int wsel = t / 9, j = t % 9;
        float a = 0.f;
        #pragma unroll
        for (int u = 0; u < 15; u++) a += smom[wsel][u][j];
        atomicAdd(&S9[((blockIdx.x * 4 + wsel) & 63) * 9 + j], a);
    }
}

// ---------------- K5: closed-form BN2a affine + per-E BN2b scale/shift ----------------
__global__ void finalize_stats(const float* __restrict__ S9,
                               const float* __restrict__ g2a, const float* __restrict__ b2a,
                               const float* __restrict__ W2a,
                               const float* __restrict__ g2b, const float* __restrict__ b2b,
                               float* __restrict__ ab, float* __restrict__ sc, float* __restrict__ sh) {
    const float cnt = (float)(BN_ * KNN);
    __shared__ float S[9];
    __shared__ float alpha[3], beta[3], mu[3], Ehh[3][3];
    int t = threadIdx.x;
    if (t < 9) {
        float a = 0.f;
        for (int u = 0; u < 64; u++) a += S9[u * 9 + t];
        S[t] = a;
    }
    __syncthreads();
    if (t == 0) {
        float m[3];
        float s2[3][3];
        s2[0][0] = S[3]; s2[1][1] = S[4]; s2[2][2] = S[5];
        s2[0][1] = s2[1][0] = S[6]; s2[0][2] = s2[2][0] = S[7]; s2[1][2] = s2[2][1] = S[8];
        for (int c = 0; c < 3; c++) {
            m[c] = S[c] / cnt;
            float var = s2[c][c] / cnt - m[c] * m[c];
            alpha[c] = g2a[c] * rsqrtf(var + EPS);
            beta[c]  = b2a[c] - m[c] * alpha[c];
            mu[c] = m[c];
            ab[c] = alpha[c]; ab[3 + c] = beta[c];
        }
        for (int c = 0; c < 3; c++)
            for (int cc = 0; cc < 3; cc++)
                Ehh[c][cc] = alpha[c] * alpha[cc] * (s2[c][cc] / cnt)
                           + alpha[c] * beta[cc] * m[c]
                           + beta[c] * alpha[cc] * m[cc]
                           + beta[c] * beta[cc];
    }
    __syncthreads();
    int e = t;
    float wv[3], Eh[3];
    for (int c = 0; c < 3; c++) { wv[c] = W2a[e * 3 + c]; Eh[c] = alpha[c] * mu[c] + beta[c]; }
    float mean = wv[0] * Eh[0] + wv[1] * Eh[1] + wv[2] * Eh[2];
    float m2 = 0.f;
    for (int c = 0; c < 3; c++)
        for (int cc = 0; cc < 3; cc++) m2 += wv[c] * wv[cc] * Ehh[c][cc];
    float var = m2 - mean * mean;
    float s = g2b[e] * rsqrtf(var + EPS);
    sc[e] = s;
    sh[e] = b2b[e] - mean * s;
}

// ---------------- K6: fused W2a→BN2b→gelu→[MFMA W2b]→max | point_emb | [MFMA Wf] ----------------
// Weight loads are tile-lane-major (base + lane*16B, coalesced).
__global__ void __launch_bounds__(256, 4) fused_final(
        const float4* __restrict__ xn4, const unsigned short* __restrict__ idx,
        const float* __restrict__ ab,
        const float* __restrict__ W2a,
        const float* __restrict__ sc, const float* __restrict__ sh,
        const unsigned short* __restrict__ w2b_t,
        const float* __restrict__ W1, const float* __restrict__ bw1,
        const unsigned short* __restrict__ wf_t, const float* __restrict__ bfv,
        float* __restrict__ out) {
    __shared__ __align__(16) unsigned short hh_bf[64 * SR];    // row n=16p+k, col e (bf16)
    __shared__ __align__(16) unsigned short feat_bf[4 * SRF];  // row p, col f 0..511 (bf16)
    __shared__ float hhat[P][3][16];
    int i0 = blockIdx.x * P;
    int t = threadIdx.x;
    int b = i0 >> 12, n0 = i0 & (N - 1);
    const float4* xb = xn4 + b * N;

    if (t < P * KNN) {   // phase A: gather + BN2a affine
        int p = t / KNN, k = t % KNN;
        int j = idx[(i0 + p) * KNN + k];
        float4 pj = xb[j];
        float4 pn = xb[n0 + p];
        hhat[p][0][k] = ab[0] * (pj.x - pn.x) + ab[3];
        hhat[p][1][k] = ab[1] * (pj.y - pn.y) + ab[4];
        hhat[p][2][k] = ab[2] * (pj.z - pn.z) + ab[5];
    }
    __syncthreads();

    {   // phase B: h = W2a @ hhat, BN2b affine, gelu (bf16 to LDS); point_emb
        int e = t;
        float w0 = W2a[e * 3], w1 = W2a[e * 3 + 1], w2 = W2a[e * 3 + 2];
        float s = sc[e], o = sh[e];
        #pragma unroll
        for (int p = 0; p < P; p++) {
            float g0 = 0.f;
            #pragma unroll
            for (int k = 0; k < KNN; k++) {
                float v = s * (w0 * hhat[p][0][k] + w1 * hhat[p][1][k] + w2 * hhat[p][2][k]) + o;
                float g = gelu_f(v);
                hh_bf[(16 * p + k) * SR + e] = f2bf(g);
                if (k == 0) g0 = g;
            }
            hh_bf[(16 * p + 15) * SR + e] = f2bf(g0);   // dup row: max unaffected
            float4 pv = xb[n0 + p];
            feat_bf[p * SRF + e] = f2bf(bw1[e] + W1[e * 3] * pv.x
                       + W1[e * 3 + 1] * pv.y + W1[e * 3 + 2] * pv.z);
        }
    }
    __syncthreads();

    int w = t >> 6, lane = t & 63;
    int m = lane & 15, q = lane >> 4;

    {   // phase C: D[k][f] = hh-tile x w2b-tile; max over k-rows -> feat_bf[:,256:512]
        int fh = w >> 1, pp = w & 1;
        bf8 hfr[2][8];
        #pragma unroll
        for (int pi = 0; pi < 2; pi++)
            #pragma unroll
            for (int kb = 0; kb < 8; kb++)
                hfr[pi][kb] = ld_bf8(&hh_bf[(16 * (pp * 2 + pi) + m) * SR + kb * 32 + q * 8]);

        const unsigned short* wbase = w2b_t + fh * 8 * 4096 + lane * 8;
        for (int ft = 0; ft < 8; ft++) {
            bf8 a[8];
            #pragma unroll
            for (int kb = 0; kb < 8; kb++)
                a[kb] = ld_bf8(wbase + ft * 4096 + kb * 512);
            #pragma unroll
            for (int pi = 0; pi < 2; pi++) {
                f4 acc = {0.f, 0.f, 0.f, 0.f};
                #pragma unroll
                for (int kb = 0; kb < 8; kb++)
                    acc = __builtin_amdgcn_mfma_f32_16x16x32_bf16(hfr[pi][kb], a[kb], acc, 0, 0, 0);
                float mx = fmaxf(fmaxf(acc[0], acc[1]), fmaxf(acc[2], acc[3]));
                mx = fmaxf(mx, __shfl_xor(mx, 16));
                mx = fmaxf(mx, __shfl_xor(mx, 32));
                if (lane < 16)
                    feat_bf[(pp * 2 + pi) * SRF + E + (fh * 8 + ft) * 16 + lane] = f2bf(mx);
            }
        }
    }
    __syncthreads();

    {   // phase D: out = Wf @ feat^T via MFMA (cols = points; feat fragments hoisted)
        bf8 fb[16];
        #pragma unroll
        for (int kb = 0; kb < 16; kb++)
            fb[kb] = ld_bf8(&feat_bf[(m & 3) * SRF + kb * 32 + q * 8]);
        const unsigned short* wfb = wf_t + w * 4 * 8192 + lane * 8;   // ot-stride 8192 (bugfix R7: was 16384)
        #pragma unroll
        for (int ot = 0; ot < 4; ot++) {
            f4 acc = {0.f, 0.f, 0.f, 0.f};
            #pragma unroll
            for (int kb = 0; kb < 16; kb++) {
                bf8 a = ld_bf8(wfb + ot * 8192 + kb * 512);
                acc = __builtin_amdgcn_mfma_f32_16x16x32_bf16(a, fb[kb], acc, 0, 0, 0);
            }
            if (m < P) {   // col = m = point; row = obase + 4q + reg
                int o0 = (w * 4 + ot) * 16 + 4 * q;
                out[(b * E + o0 + 0) * N + n0 + m] = acc[0] + bfv[o0 + 0];
                out[(b * E + o0 + 1) * N + n0 + m] = acc[1] + bfv[o0 + 1];
                out[(b * E + o0 + 2) * N + n0 + m] = acc[2] + bfv[o0 + 2];
                out[(b * E + o0 + 3) * N + n0 + m] = acc[3] + bfv[o0 + 3];
            }
        }
    }
}

extern "C" void kernel_launch(void* const* d_in, const int* in_sizes, int n_in,
                              void* d_out, int out_size, void* d_ws, size_t ws_size,
                              hipStream_t stream) {
    (void)in_sizes; (void)n_in; (void)out_size; (void)ws_size;
    const float* x   = (const float*)d_in[0];
    const float* g1  = (const float*)d_in[1];
    const float* b1  = (const float*)d_in[2];
    const float* W1  = (const float*)d_in[3];
    const float* bw1 = (const float*)d_in[4];
    const float* g2a = (const float*)d_in[5];
    const float* b2a = (const float*)d_in[6];
    const float* W2a = (const float*)d_in[7];
    const float* g2b = (const float*)d_in[8];
    const float* b2b = (const float*)d_in[9];
    const float* W2b = (const float*)d_in[10];
    const float* Wf  = (const float*)d_in[11];
    const float* bfv = (const float*)d_in[12];
    float* out = (float*)d_out;

    char* ws = (char*)d_ws;
    size_t off = 0;
    auto alloc = [&](size_t bytes) { size_t o = off; off = (off + bytes + 255) & ~(size_t)255; return o; };
    float4* xn4           = (float4*)(ws + alloc(sizeof(float4) * BN_));
    unsigned short* idx   = (unsigned short*)(ws + alloc(sizeof(unsigned short) * BN_ * KNN));
    float* bn1            = (float*)(ws + alloc(sizeof(float) * 8));
    float* S9             = (float*)(ws + alloc(sizeof(float) * 64 * 9));
    float* ab             = (float*)(ws + alloc(sizeof(float) * 8));
    float* sc             = (float*)(ws + alloc(sizeof(float) * E));
    float* sh             = (float*)(ws + alloc(sizeof(float) * E));
    unsigned short* w2bt  = (unsigned short*)(ws + alloc(sizeof(unsigned short) * E * E));
    unsigned short* wft   = (unsigned short*)(ws + alloc(sizeof(unsigned short) * E * 2 * E));

    hipMemsetAsync(S9, 0, sizeof(float) * 64 * 9, stream);

    bn1_stats<<<C, 256, 0, stream>>>(x, bn1);
    compute_xn_cvt<<<BN_ / 256 + (8192 + 16384) / 256, 256, 0, stream>>>(
        x, g1, b1, bn1, xn4, W2b, Wf, w2bt, wft);
    knn_kernel<<<BN_ / 4, 256, 0, stream>>>(xn4, idx, S9);
    finalize_stats<<<1, 256, 0, stream>>>(S9, g2a, b2a, W2a, g2b, b2b, ab, sc, sh);
    fused_final<<<BN_ / P, 256, 0, stream>>>(xn4, idx, ab, W2a, sc, sh, w2bt, W1, bw1, wft, bfv, out);
}